// Round 4
// baseline (566.318 us; speedup 1.0000x reference)
//
#include <hip/hip_runtime.h>
#include <math.h>

#define MIN_D (-3.402823466e+38f)

constexpr int Bb = 2, Ss = 2048, Dm = 1024, Hh = 16, HDd = 64, NV = 8192, DRr = 128;
constexpr int Mrows = Bb * Ss;   // 4096
constexpr float MARGIN = 0.05f;  // >> 6-sigma of bf16 sim error (~5e-3)
constexpr int CAP = 65536;       // candidate-pair buffer

typedef __attribute__((ext_vector_type(8))) short bf16x8;
typedef __attribute__((ext_vector_type(4))) float f32x4;

__device__ inline unsigned short f2bf(float x) {
    union { float f; unsigned u; } v; v.f = x;
    unsigned r = v.u + 0x7fff + ((v.u >> 16) & 1);   // RNE
    return (unsigned short)(r >> 16);
}
__device__ inline float bf2f(unsigned short u) {
    union { unsigned u; float f; } v; v.u = ((unsigned)u) << 16;
    return v.f;
}

// ---------------------------------------------------------------------------
// f32 -> bf16 elementwise. 8 elems/thread; grid = n/2048.
// ---------------------------------------------------------------------------
__global__ __launch_bounds__(256)
void cvt_bf16(const float* __restrict__ x, unsigned short* __restrict__ y)
{
    size_t i = ((size_t)blockIdx.x * 256 + threadIdx.x) * 8;
    float4 a = *(const float4*)(x + i);
    float4 b = *(const float4*)(x + i + 4);
    uint4 p;
    p.x = (unsigned)f2bf(a.x) | ((unsigned)f2bf(a.y) << 16);
    p.y = (unsigned)f2bf(a.z) | ((unsigned)f2bf(a.w) << 16);
    p.z = (unsigned)f2bf(b.x) | ((unsigned)f2bf(b.y) << 16);
    p.w = (unsigned)f2bf(b.z) | ((unsigned)f2bf(b.w) << 16);
    *(uint4*)(y + i) = p;
}

// ---------------------------------------------------------------------------
// Transpose + convert: W[K][N] f32 -> WT[N][K] bf16. 64x64 tiles.
// ---------------------------------------------------------------------------
__global__ __launch_bounds__(256)
void transpose_cvt(const float* __restrict__ W, unsigned short* __restrict__ WT,
                   int K, int N)
{
    __shared__ unsigned short T[64][72];
    const int tid = threadIdx.x;
    const int n0 = blockIdx.x * 64, k0 = blockIdx.y * 64;
    const int rr = tid >> 4, cc = tid & 15;
#pragma unroll
    for (int q2 = 0; q2 < 4; ++q2) {
        int kk = rr * 4 + q2;
        float4 v = *(const float4*)(W + (size_t)(k0 + kk) * N + n0 + cc * 4);
        T[cc * 4 + 0][kk] = f2bf(v.x);
        T[cc * 4 + 1][kk] = f2bf(v.y);
        T[cc * 4 + 2][kk] = f2bf(v.z);
        T[cc * 4 + 3][kk] = f2bf(v.w);
    }
    __syncthreads();
#pragma unroll
    for (int q2 = 0; q2 < 4; ++q2) {
        int nn = rr * 4 + q2;
        uint2 u;
        u.x = (unsigned)T[nn][cc * 4 + 0] | ((unsigned)T[nn][cc * 4 + 1] << 16);
        u.y = (unsigned)T[nn][cc * 4 + 2] | ((unsigned)T[nn][cc * 4 + 3] << 16);
        *(uint2*)(WT + (size_t)(n0 + nn) * K + k0 + cc * 4) = u;
    }
}

// ---------------------------------------------------------------------------
// bf16 MFMA GEMM: C[M,N] = A[M,K] @ BT[N,K]^T + bias[N]  (unchanged from R3)
// ---------------------------------------------------------------------------
template<bool BF16OUT>
__global__ __launch_bounds__(256)
void gemm_bf16(const unsigned short* __restrict__ A,
               const unsigned short* __restrict__ BT,
               const float* __restrict__ bias, void* __restrict__ C,
               int M, int N, int K)
{
    __shared__ __align__(16) unsigned short As[128 * 32];
    __shared__ __align__(16) unsigned short Bs[64 * 32];
    const int tid = threadIdx.x;
    const int l = tid & 63, w = tid >> 6;
    const int l15 = l & 15, l4 = l >> 4;
    const int wm = w >> 1, wn = w & 1;
    const int row0 = blockIdx.y * 128, col0 = blockIdx.x * 64;

    f32x4 acc[4][2];
#pragma unroll
    for (int mi = 0; mi < 4; ++mi)
#pragma unroll
        for (int ni = 0; ni < 2; ++ni) acc[mi][ni] = (f32x4)(0.f);

    for (int k0 = 0; k0 < K; k0 += 32) {
        __syncthreads();
#pragma unroll
        for (int q2 = 0; q2 < 2; ++q2) {
            int o = q2 * 256 + tid;
            int r = o >> 2, pc = o & 3;
            uint4 vv = *(const uint4*)(A + (size_t)(row0 + r) * K + k0 + pc * 8);
            *(uint4*)&As[o * 8] = vv;
        }
        {
            int r = tid >> 2, pc = tid & 3;
            uint4 vv = *(const uint4*)(BT + (size_t)(col0 + r) * K + k0 + pc * 8);
            *(uint4*)&Bs[tid * 8] = vv;
        }
        __syncthreads();

        bf16x8 af[4], bf[2];
#pragma unroll
        for (int mi = 0; mi < 4; ++mi)
            af[mi] = *(bf16x8*)&As[(wm * 64 + mi * 16 + l15) * 32 + l4 * 8];
#pragma unroll
        for (int ni = 0; ni < 2; ++ni)
            bf[ni] = *(bf16x8*)&Bs[(wn * 32 + ni * 16 + l15) * 32 + l4 * 8];
#pragma unroll
        for (int mi = 0; mi < 4; ++mi)
#pragma unroll
            for (int ni = 0; ni < 2; ++ni)
                acc[mi][ni] = __builtin_amdgcn_mfma_f32_16x16x32_bf16(af[mi], bf[ni], acc[mi][ni], 0, 0, 0);
    }

#pragma unroll
    for (int mi = 0; mi < 4; ++mi)
#pragma unroll
        for (int ni = 0; ni < 2; ++ni)
#pragma unroll
            for (int j = 0; j < 4; ++j) {
                int row = row0 + wm * 64 + mi * 16 + l4 * 4 + j;
                int col = col0 + wn * 32 + ni * 16 + l15;
                float vv = acc[mi][ni][j] + bias[col];
                if (BF16OUT)
                    ((unsigned short*)C)[(size_t)row * N + col] = f2bf(vv);
                else
                    ((float*)C)[(size_t)row * N + col] = vv;
            }
}

// ---------------------------------------------------------------------------
// f32 GEMM for vq projection (N=128) — exact, feeds the argmax rescore.
// ---------------------------------------------------------------------------
__global__ __launch_bounds__(256)
void gemm_bias_f32(const float* __restrict__ A, const float* __restrict__ W,
                   const float* __restrict__ bias, float* __restrict__ C,
                   int N, int K)
{
    __shared__ float As[64][20];
    __shared__ float Ws[16][64];
    const int tid = threadIdx.x;
    const int row0 = blockIdx.y * 64, col0 = blockIdx.x * 64;
    const int tr = tid >> 4, tc = tid & 15;
    float acc[4][4] = {};

    for (int k0 = 0; k0 < K; k0 += 16) {
        {
            int r = tid >> 2, c4 = (tid & 3) << 2;
            float4 av = *(const float4*)(A + (size_t)(row0 + r) * K + k0 + c4);
            *(float4*)&As[r][c4] = av;
        }
        {
            int r = tid >> 4, c4 = (tid & 15) << 2;
            float4 wv = *(const float4*)(W + (size_t)(k0 + r) * N + col0 + c4);
            *(float4*)&Ws[r][c4] = wv;
        }
        __syncthreads();
#pragma unroll
        for (int kk = 0; kk < 16; ++kk) {
            float a[4];
#pragma unroll
            for (int i = 0; i < 4; ++i) a[i] = As[tr * 4 + i][kk];
            float4 bv = *(const float4*)&Ws[kk][tc * 4];
            float b[4] = {bv.x, bv.y, bv.z, bv.w};
#pragma unroll
            for (int i = 0; i < 4; ++i)
#pragma unroll
                for (int j = 0; j < 4; ++j)
                    acc[i][j] = fmaf(a[i], b[j], acc[i][j]);
        }
        __syncthreads();
    }
#pragma unroll
    for (int i = 0; i < 4; ++i) {
        int r = row0 + tr * 4 + i;
        int c = col0 + tc * 4;
        float4 ov;
        ov.x = acc[i][0] + bias[c + 0];
        ov.y = acc[i][1] + bias[c + 1];
        ov.z = acc[i][2] + bias[c + 2];
        ov.w = acc[i][3] + bias[c + 3];
        *(float4*)(C + (size_t)r * N + c) = ov;
    }
}

// ---------------------------------------------------------------------------
// Retrieval phase 1: bf16 MFMA sim, per-(row, 1024-key-chunk) maxima.
// Block = 256 thr = 4 waves; wave w: rows row0+w*16.. ; grid (64, 8).
// No LDS: vq_hi (1MB) and vk_hi (2MB) are L2-resident.
// ---------------------------------------------------------------------------
__global__ __launch_bounds__(256)
void sim_phase1(const unsigned short* __restrict__ vq_hi,
                const unsigned short* __restrict__ vk_hi,
                float* __restrict__ pm1)
{
    const int tid = threadIdx.x;
    const int l = tid & 63, w = tid >> 6;
    const int l15 = l & 15, l4 = l >> 4;
    const int row0 = blockIdx.x * 64;
    const int chunk = blockIdx.y;

    bf16x8 af[4];
#pragma unroll
    for (int kk = 0; kk < 4; ++kk)
        af[kk] = *(const bf16x8*)(vq_hi + (size_t)(row0 + w * 16 + l15) * 128 + kk * 32 + l4 * 8);

    float vmax[4] = {-INFINITY, -INFINITY, -INFINITY, -INFINITY};

#pragma unroll 2
    for (int t = 0; t < 64; ++t) {
        const int key = chunk * 1024 + t * 16 + l15;
        const unsigned short* kp = vk_hi + (size_t)key * 128 + l4 * 8;
        f32x4 s = (f32x4)(0.f);
#pragma unroll
        for (int kk = 0; kk < 4; ++kk) {
            bf16x8 bfr = *(const bf16x8*)(kp + kk * 32);
            s = __builtin_amdgcn_mfma_f32_16x16x32_bf16(af[kk], bfr, s, 0, 0, 0);
        }
#pragma unroll
        for (int j = 0; j < 4; ++j) vmax[j] = fmaxf(vmax[j], s[j]);
    }
#pragma unroll
    for (int off = 1; off < 16; off <<= 1)
#pragma unroll
        for (int j = 0; j < 4; ++j)
            vmax[j] = fmaxf(vmax[j], __shfl_xor(vmax[j], off));
    if (l15 == 0) {
#pragma unroll
        for (int j = 0; j < 4; ++j)
            pm1[(row0 + w * 16 + l4 * 4 + j) * 8 + chunk] = vmax[j];
    }
}

__global__ void sim_combine(const float* __restrict__ pm1, float* __restrict__ thr)
{
    int r = blockIdx.x * 256 + threadIdx.x;
    if (r >= Mrows) return;
    float m = pm1[r * 8];
#pragma unroll
    for (int c = 1; c < 8; ++c) m = fmaxf(m, pm1[r * 8 + c]);
    thr[r] = m - MARGIN;
}

// ---------------------------------------------------------------------------
// Retrieval phase 2: recompute bf16 sim, push candidates >= thr[row].
// ---------------------------------------------------------------------------
__global__ __launch_bounds__(256)
void sim_phase2(const unsigned short* __restrict__ vq_hi,
                const unsigned short* __restrict__ vk_hi,
                const float* __restrict__ thr,
                unsigned* __restrict__ cnt, unsigned* __restrict__ pairs)
{
    const int tid = threadIdx.x;
    const int l = tid & 63, w = tid >> 6;
    const int l15 = l & 15, l4 = l >> 4;
    const int row0 = blockIdx.x * 64;
    const int chunk = blockIdx.y;

    bf16x8 af[4];
#pragma unroll
    for (int kk = 0; kk < 4; ++kk)
        af[kk] = *(const bf16x8*)(vq_hi + (size_t)(row0 + w * 16 + l15) * 128 + kk * 32 + l4 * 8);

    float th[4];
    int rowj[4];
#pragma unroll
    for (int j = 0; j < 4; ++j) {
        rowj[j] = row0 + w * 16 + l4 * 4 + j;
        th[j] = thr[rowj[j]];
    }

#pragma unroll 2
    for (int t = 0; t < 64; ++t) {
        const int key = chunk * 1024 + t * 16 + l15;
        const unsigned short* kp = vk_hi + (size_t)key * 128 + l4 * 8;
        f32x4 s = (f32x4)(0.f);
#pragma unroll
        for (int kk = 0; kk < 4; ++kk) {
            bf16x8 bfr = *(const bf16x8*)(kp + kk * 32);
            s = __builtin_amdgcn_mfma_f32_16x16x32_bf16(af[kk], bfr, s, 0, 0, 0);
        }
#pragma unroll
        for (int j = 0; j < 4; ++j) {
            if (s[j] >= th[j]) {
                unsigned slot = atomicAdd(cnt, 1u);
                if (slot < (unsigned)CAP)
                    pairs[slot] = ((unsigned)rowj[j] << 13) | (unsigned)key;
            }
        }
    }
}

// ---------------------------------------------------------------------------
// Exact f32 rescore of candidates; first-index argmax via u64 atomicMax.
// enc = flipfloat(sim) << 32 | ~key  (larger = better; ties -> smaller key).
// ---------------------------------------------------------------------------
__global__ __launch_bounds__(256)
void sim_rescore(const unsigned* __restrict__ pairs, const unsigned* __restrict__ cnt,
                 const float* __restrict__ vq, const float* __restrict__ vkeys,
                 unsigned long long* __restrict__ best)
{
    const int l = threadIdx.x & 63;
    const unsigned wav = (blockIdx.x * 256 + threadIdx.x) >> 6;
    const unsigned nw = (gridDim.x * 256) >> 6;
    const unsigned n = min(*cnt, (unsigned)CAP);
    for (unsigned i = wav; i < n; i += nw) {
        unsigned p = pairs[i];
        unsigned row = p >> 13, key = p & 8191u;
        float2 a = *(const float2*)(vq + (size_t)row * 128 + l * 2);
        float2 b = *(const float2*)(vkeys + (size_t)key * 128 + l * 2);
        float d = a.x * b.x + a.y * b.y;
#pragma unroll
        for (int off = 32; off; off >>= 1) d += __shfl_xor(d, off);
        if (l == 0) {
            unsigned fb = __float_as_uint(d);
            fb = (fb & 0x80000000u) ? ~fb : (fb | 0x80000000u);
            unsigned long long enc = ((unsigned long long)fb << 32) | (unsigned)(~key);
            atomicMax(best + row, enc);
        }
    }
}

// ---------------------------------------------------------------------------
// v = hs * v_embed[idx], bf16 out; idx decoded from best[].
// ---------------------------------------------------------------------------
__global__ __launch_bounds__(256)
void build_v_bf16(const float* __restrict__ hs, const float* __restrict__ vembed,
                  const unsigned long long* __restrict__ best,
                  unsigned short* __restrict__ v)
{
    int row = blockIdx.x;
    int id = (int)((~(unsigned)(best[row] & 0xFFFFFFFFull)) & 8191u);
    int c = threadIdx.x * 4;
    float4 a = *(const float4*)(hs + (size_t)row * Dm + c);
    float4 e = *(const float4*)(vembed + (size_t)id * Dm + c);
    uint2 u;
    u.x = (unsigned)f2bf(a.x * e.x) | ((unsigned)f2bf(a.y * e.y) << 16);
    u.y = (unsigned)f2bf(a.z * e.z) | ((unsigned)f2bf(a.w * e.w) << 16);
    *(uint2*)(v + (size_t)row * Dm + c) = u;
}

// ---------------------------------------------------------------------------
// meanv[b][d] = mean over s of v (bf16 in, f32 out) — fully-masked rows.
// ---------------------------------------------------------------------------
__global__ __launch_bounds__(256)
void mean_v_kernel(const unsigned short* __restrict__ v, float* __restrict__ mv)
{
    __shared__ float part[4][64];
    const int d0 = blockIdx.x * 64;
    const int b  = blockIdx.y;
    const int dl = threadIdx.x & 63, jc = threadIdx.x >> 6;
    float s = 0.f;
#pragma unroll 4
    for (int j = jc * 512; j < jc * 512 + 512; ++j)
        s += bf2f(v[((size_t)(b * Ss + j)) * Dm + d0 + dl]);
    part[jc][dl] = s;
    __syncthreads();
    if (threadIdx.x < 64) {
        float t = part[0][dl] + part[1][dl] + part[2][dl] + part[3][dl];
        mv[b * Dm + d0 + dl] = t * (1.f / 2048.f);
    }
}

// ---------------------------------------------------------------------------
// bf16 MFMA flash attention v3 — SWAPPED QK^T (S^T = K·Q^T).
// Lane owns q = l&15 column: softmax reduce = in-reg + 2 shuffles; scalar
// mrun/lrun; lane-uniform rescale; P stored as b64 swizzled writes.
// PV: out^T = V^T · P^T (same Vsm frag reads as R3); epilogue transposed
// through LDS for coalesced stores. Frag addressing identical to R3
// (verified); only operand roles swap.
// ---------------------------------------------------------------------------
__global__ __launch_bounds__(256)
void attn_mfma3(const unsigned short* __restrict__ q, const unsigned short* __restrict__ k,
                const unsigned short* __restrict__ v, const float* __restrict__ am,
                const float* __restrict__ dm, const float* __restrict__ meanv,
                unsigned short* __restrict__ o)
{
    __shared__ __align__(16) unsigned char smem[24576];   // K 8K | V 8K | P 8K ; epilogue: f32 stage
    __shared__ unsigned char mb[256];
    __shared__ float uniflag[64];
    unsigned char* Ksm = smem;
    unsigned char* Vsm = smem + 8192;
    unsigned char* Psm = smem + 16384;

    const int tid = threadIdx.x;
    const int l = tid & 63, w = tid >> 6;
    const int l15 = l & 15, l4 = l >> 4;
    const int qt = gridDim.x - 1 - blockIdx.x;   // heavy tiles first
    const int h = blockIdx.y, b = blockIdx.z;
    const int row0 = qt * 64;

    {   // 2048-bit mask: bit=1 means masked (am*dm == 0)
        unsigned byte = 0;
#pragma unroll
        for (int j = 0; j < 8; ++j) {
            int c = tid * 8 + j;
            byte |= (unsigned)((am[b * Ss + c] * dm[h * Ss + c]) == 0.f) << j;
        }
        mb[tid] = (unsigned char)byte;
    }

    const int qrow = row0 + w * 16 + l15;        // this lane's q column
    bf16x8 qf[2];
    {
        const unsigned short* qp = q + ((size_t)(b * Ss + qrow)) * Dm + h * HDd + l4 * 8;
        qf[0] = *(const bf16x8*)qp;
        qf[1] = *(const bf16x8*)(qp + 32);
    }

    f32x4 acc[4];                                // [d2]: rows d, col q=l15
#pragma unroll
    for (int d2 = 0; d2 < 4; ++d2) acc[d2] = (f32x4)(0.f);
    float mrun = -INFINITY, lrun = 0.f;

    for (int kt = 0; kt <= qt; ++kt) {
        __syncthreads();
        {   // K stage: source chunk-swizzled, LDS linear (R3-verified)
#pragma unroll
            for (int q2 = 0; q2 < 2; ++q2) {
                int ochunk = q2 * 256 + tid;
                int key = ochunk >> 3, pc = ochunk & 7;
                int lc = pc ^ (key & 7);
                uint4 vv = *(const uint4*)(k + ((size_t)(b * Ss + kt * 64 + key)) * Dm
                                           + h * HDd + lc * 8);
                *(uint4*)&Ksm[ochunk * 16] = vv;
            }
        }
        {   // V stage transposed [d][key], b128 swizzled writes (R3-verified)
            const unsigned short* vp = v + ((size_t)(b * Ss + kt * 64 + w * 16)) * Dm
                                       + h * HDd + l;
            unsigned vr[8];
#pragma unroll
            for (int j2 = 0; j2 < 8; ++j2) {
                unsigned lo = vp[(size_t)(2 * j2) * Dm];
                unsigned hi = vp[(size_t)(2 * j2 + 1) * Dm];
                vr[j2] = lo | (hi << 16);
            }
            const unsigned swz = (l & 7) << 4;
            uint4 a0; a0.x = vr[0]; a0.y = vr[1]; a0.z = vr[2]; a0.w = vr[3];
            uint4 a1; a1.x = vr[4]; a1.y = vr[5]; a1.z = vr[6]; a1.w = vr[7];
            *(uint4*)&Vsm[l * 128 + ((w * 32) ^ swz)]      = a0;
            *(uint4*)&Vsm[l * 128 + ((w * 32 + 16) ^ swz)] = a1;
        }
        __syncthreads();

        // S^T = K Q^T  (A=K frag row=key, B=Q frag col=q)
        f32x4 sreg[4];
#pragma unroll
        for (int kb = 0; kb < 4; ++kb) {
            const int key16 = kb * 16 + l15;
            const int sw = key16 & 7;
            bf16x8 k0 = *(bf16x8*)&Ksm[key16 * 128 + ((l4 ^ sw) * 16)];
            bf16x8 k1 = *(bf16x8*)&Ksm[key16 * 128 + (((4 + l4) ^ sw) * 16)];
            f32x4 s = (f32x4)(0.f);
            s = __builtin_amdgcn_mfma_f32_16x16x32_bf16(k0, qf[0], s, 0, 0, 0);
            s = __builtin_amdgcn_mfma_f32_16x16x32_bf16(k1, qf[1], s, 0, 0, 0);
            sreg[kb] = s;
        }

        // mask + scale; scores: sv[kb*4+r] = S[key=kt*64+kb*16+l4*4+r][qrow]
        float sv[16];
#pragma unroll
        for (int kb = 0; kb < 4; ++kb)
#pragma unroll
            for (int r = 0; r < 4; ++r) {
                const int key = kt * 64 + kb * 16 + l4 * 4 + r;
                const bool masked = (key > qrow) || ((mb[key >> 3] >> (key & 7)) & 1);
                sv[kb * 4 + r] = sreg[kb][r] * 0.125f + (masked ? MIN_D : 0.f);
            }

        // online softmax: in-reg max + 2 shuffles (across l4 groups)
        float pm = sv[0];
#pragma unroll
        for (int i = 1; i < 16; ++i) pm = fmaxf(pm, sv[i]);
        pm = fmaxf(pm, __shfl_xor(pm, 16));
        pm = fmaxf(pm, __shfl_xor(pm, 32));
        const float mn = fmaxf(mrun, pm);
        const float sc = __expf(mrun - mn);
        float p[16], rs = 0.f;
#pragma unroll
        for (int i = 0; i < 16; ++i) { p[i] = __expf(sv[i] - mn); rs += p[i]; }
        rs += __shfl_xor(rs, 16);
        rs += __shfl_xor(rs, 32);
        lrun = lrun * sc + rs;
        mrun = mn;
#pragma unroll
        for (int d2 = 0; d2 < 4; ++d2) acc[d2] *= sc;

        // P store: Psm[q=w*16+l15][key] bf16, b64 swizzled writes
        const int qloc = w * 16 + l15;
        const unsigned pswz = (l15 & 7) << 4;
#pragma unroll
        for (int kb = 0; kb < 4; ++kb) {
            uint2 u;
            u.x = (unsigned)f2bf(p[kb * 4 + 0]) | ((unsigned)f2bf(p[kb * 4 + 1]) << 16);
            u.y = (unsigned)f2bf(p[kb * 4 + 2]) | ((unsigned)f2bf(p[kb * 4 + 3]) << 16);
            *(uint2*)&Psm[qloc * 128 + ((kb * 32 + l4 * 8) ^ pswz)] = u;
        }

        // O^T += V^T P^T  (A = V^T frag row=d, B = P^T frag col=q) — same-wave
        // LDS write->read, in-order, no barrier needed.
#pragma unroll
        for (int ks = 0; ks < 2; ++ks) {
            bf16x8 pa = *(bf16x8*)&Psm[qloc * 128 + ((ks * 64 + l4 * 16) ^ pswz)];
#pragma unroll
            for (int d2 = 0; d2 < 4; ++d2) {
                const int dd = d2 * 16 + l15;
                bf16x8 vb = *(bf16x8*)&Vsm[dd * 128 + ((ks * 64 + l4 * 16) ^ ((dd & 7) << 4))];
                acc[d2] = __builtin_amdgcn_mfma_f32_16x16x32_bf16(vb, pa, acc[d2], 0, 0, 0);
            }
        }
    }

    // epilogue: transpose through LDS for coalesced bf16 stores
    const float inv = 1.f / lrun;
    const bool uni = (mrun <= -1e37f);
    __syncthreads();                       // all waves done with K/V/P LDS
    float* stage = (float*)smem;           // [64][65] f32 = 16640B
    uniflag[w * 16 + l15] = uni ? 1.f : 0.f;
#pragma unroll
    for (int d2 = 0; d2 < 4; ++d2)
#pragma unroll
        for (int j = 0; j < 4; ++j)
            stage[(w * 16 + l15) * 65 + d2 * 16 + l4 * 4 + j] = acc[d2][j] * inv;
    __syncthreads();
    {
        const int r = tid >> 2, c0 = (tid & 3) * 16;
        const bool u = uniflag[r] != 0.f;
        unsigned short ob[16];
#pragma unroll
        for (int i = 0; i < 16; ++i) {
            float val = u ? meanv[b * Dm + h * HDd + c0 + i] : stage[r * 65 + c0 + i];
            ob[i] = f2bf(val);
        }
        unsigned short* op = o + ((size_t)(b * Ss + row0 + r)) * Dm + h * HDd + c0;
        *(uint4*)op = *(uint4*)&ob[0];
        *(uint4*)(op + 8) = *(uint4*)&ob[8];
    }
}

// ---------------------------------------------------------------------------
extern "C" void kernel_launch(void* const* d_in, const int* in_sizes, int n_in,
                              void* d_out, int out_size, void* d_ws, size_t ws_size,
                              hipStream_t stream)
{
    const float* hs     = (const float*)d_in[0];
    const float* amask  = (const float*)d_in[1];
    const float* Wq     = (const float*)d_in[2];
    const float* bq     = (const float*)d_in[3];
    const float* Wk     = (const float*)d_in[4];
    const float* bk     = (const float*)d_in[5];
    const float* dmask  = (const float*)d_in[6];
    const float* Wvq    = (const float*)d_in[7];
    const float* bvq    = (const float*)d_in[8];
    const float* vkeys  = (const float*)d_in[9];
    const float* vembed = (const float*)d_in[10];
    const float* Wo     = (const float*)d_in[11];
    const float* bo     = (const float*)d_in[12];
    float* out = (float*)d_out;

    char* w = (char*)d_ws;
    size_t off = 0;
    auto take = [&](size_t n) { char* p = w + off; off = (off + n + 255) & ~(size_t)255; return p; };
    unsigned short* hsbf  = (unsigned short*)take((size_t)Mrows * Dm * 2);
    unsigned short* WqT   = (unsigned short*)take((size_t)Dm * Dm * 2);
    unsigned short* WkT   = (unsigned short*)take((size_t)Dm * Dm * 2);
    unsigned short* WoT   = (unsigned short*)take((size_t)Dm * Dm * 2);
    unsigned short* qbf   = (unsigned short*)take((size_t)Mrows * Dm * 2);
    unsigned short* kbf   = (unsigned short*)take((size_t)Mrows * Dm * 2);
    unsigned short* vbuf  = (unsigned short*)take((size_t)Mrows * Dm * 2);
    unsigned short* attno = (unsigned short*)take((size_t)Mrows * Dm * 2);
    float* vqb   = (float*)take((size_t)Mrows * DRr * 4);
    unsigned short* vq_hi = (unsigned short*)take((size_t)Mrows * DRr * 2);
    unsigned short* vk_hi = (unsigned short*)take((size_t)NV * DRr * 2);
    float* pm1   = (float*)take((size_t)Mrows * 8 * 4);
    float* thr   = (float*)take((size_t)Mrows * 4);
    unsigned* cnt = (unsigned*)take(256);
    unsigned* pairs = (unsigned*)take((size_t)CAP * 4);
    unsigned long long* best = (unsigned long long*)take((size_t)Mrows * 8);
    float* mvb   = (float*)take((size_t)Bb * Dm * 4);

    // zero atomics state (graph-capture-safe)
    hipMemsetAsync(cnt, 0, 4, stream);
    hipMemsetAsync(best, 0, (size_t)Mrows * 8, stream);

    dim3 blk(256);
    // dtype prep
    cvt_bf16<<<dim3(Mrows * Dm / 2048), blk, 0, stream>>>(hs, hsbf);
    transpose_cvt<<<dim3(Dm / 64, Dm / 64), blk, 0, stream>>>(Wq, WqT, Dm, Dm);
    transpose_cvt<<<dim3(Dm / 64, Dm / 64), blk, 0, stream>>>(Wk, WkT, Dm, Dm);
    transpose_cvt<<<dim3(Dm / 64, Dm / 64), blk, 0, stream>>>(Wo, WoT, Dm, Dm);
    // projections (bf16 MFMA)
    gemm_bf16<true><<<dim3(Dm / 64, Mrows / 128), blk, 0, stream>>>(hsbf, WqT, bq, qbf, Mrows, Dm, Dm);
    gemm_bf16<true><<<dim3(Dm / 64, Mrows / 128), blk, 0, stream>>>(hsbf, WkT, bk, kbf, Mrows, Dm, Dm);
    // retrieval: exact vq, bf16 screen, exact rescore
    gemm_bias_f32<<<dim3(DRr / 64, Mrows / 64), blk, 0, stream>>>(hs, Wvq, bvq, vqb, DRr, Dm);
    cvt_bf16<<<dim3(Mrows * DRr / 2048), blk, 0, stream>>>(vqb, vq_hi);
    cvt_bf16<<<dim3(NV * DRr / 2048), blk, 0, stream>>>(vkeys, vk_hi);
    sim_phase1<<<dim3(Mrows / 64, 8), blk, 0, stream>>>(vq_hi, vk_hi, pm1);
    sim_combine<<<dim3((Mrows + 255) / 256), blk, 0, stream>>>(pm1, thr);
    sim_phase2<<<dim3(Mrows / 64, 8), blk, 0, stream>>>(vq_hi, vk_hi, thr, cnt, pairs);
    sim_rescore<<<dim3(256), blk, 0, stream>>>(pairs, cnt, vqb, vkeys, best);
    build_v_bf16<<<dim3(Mrows), blk, 0, stream>>>(hs, vembed, best, vbuf);
    mean_v_kernel<<<dim3(Dm / 64, Bb), blk, 0, stream>>>(vbuf, mvb);
    // attention
    attn_mfma3<<<dim3(Ss / 64, Hh, Bb), blk, 0, stream>>>(qbf, kbf, vbuf, amask, dmask, mvb, attno);
    // output projection (f32 out)
    gemm_bf16<false><<<dim3(Dm / 64, Mrows / 128), blk, 0, stream>>>(attno, WoT, bo, out, Mrows, Dm, Dm);
}

// Round 5
// 408.830 us; speedup vs baseline: 1.3852x; 1.3852x over previous
//
#include <hip/hip_runtime.h>
#include <math.h>

#define MIN_D (-3.402823466e+38f)

constexpr int Bb = 2, Ss = 2048, Dm = 1024, Hh = 16, HDd = 64, NV = 8192, DRr = 128;
constexpr int Mrows = Bb * Ss;   // 4096
constexpr float MARGIN = 0.01f;  // ~22 sigma of bf16 sim error (4.5e-4)
constexpr int CAP = 65536;       // candidate-pair buffer

typedef __attribute__((ext_vector_type(8))) short bf16x8;
typedef __attribute__((ext_vector_type(4))) float f32x4;

__device__ inline unsigned short f2bf(float x) {
    union { float f; unsigned u; } v; v.f = x;
    unsigned r = v.u + 0x7fff + ((v.u >> 16) & 1);   // RNE
    return (unsigned short)(r >> 16);
}
__device__ inline float bf2f(unsigned short u) {
    union { unsigned u; float f; } v; v.u = ((unsigned)u) << 16;
    return v.f;
}

// ---------------------------------------------------------------------------
// f32 -> bf16 elementwise. 8 elems/thread; grid = n/2048.
// ---------------------------------------------------------------------------
__global__ __launch_bounds__(256)
void cvt_bf16(const float* __restrict__ x, unsigned short* __restrict__ y)
{
    size_t i = ((size_t)blockIdx.x * 256 + threadIdx.x) * 8;
    float4 a = *(const float4*)(x + i);
    float4 b = *(const float4*)(x + i + 4);
    uint4 p;
    p.x = (unsigned)f2bf(a.x) | ((unsigned)f2bf(a.y) << 16);
    p.y = (unsigned)f2bf(a.z) | ((unsigned)f2bf(a.w) << 16);
    p.z = (unsigned)f2bf(b.x) | ((unsigned)f2bf(b.y) << 16);
    p.w = (unsigned)f2bf(b.z) | ((unsigned)f2bf(b.w) << 16);
    *(uint4*)(y + i) = p;
}

// ---------------------------------------------------------------------------
// Transpose + convert: W[K][N] f32 -> WT[N][K] bf16. 64x64 tiles.
// ---------------------------------------------------------------------------
__global__ __launch_bounds__(256)
void transpose_cvt(const float* __restrict__ W, unsigned short* __restrict__ WT,
                   int K, int N)
{
    __shared__ unsigned short T[64][72];
    const int tid = threadIdx.x;
    const int n0 = blockIdx.x * 64, k0 = blockIdx.y * 64;
    const int rr = tid >> 4, cc = tid & 15;
#pragma unroll
    for (int q2 = 0; q2 < 4; ++q2) {
        int kk = rr * 4 + q2;
        float4 v = *(const float4*)(W + (size_t)(k0 + kk) * N + n0 + cc * 4);
        T[cc * 4 + 0][kk] = f2bf(v.x);
        T[cc * 4 + 1][kk] = f2bf(v.y);
        T[cc * 4 + 2][kk] = f2bf(v.z);
        T[cc * 4 + 3][kk] = f2bf(v.w);
    }
    __syncthreads();
#pragma unroll
    for (int q2 = 0; q2 < 4; ++q2) {
        int nn = rr * 4 + q2;
        uint2 u;
        u.x = (unsigned)T[nn][cc * 4 + 0] | ((unsigned)T[nn][cc * 4 + 1] << 16);
        u.y = (unsigned)T[nn][cc * 4 + 2] | ((unsigned)T[nn][cc * 4 + 3] << 16);
        *(uint2*)(WT + (size_t)(n0 + nn) * K + k0 + cc * 4) = u;
    }
}

// ---------------------------------------------------------------------------
// bf16 MFMA GEMM: C[M,N] = A[M,K] @ BT[N,K]^T + bias[N]  (unchanged)
// ---------------------------------------------------------------------------
template<bool BF16OUT>
__global__ __launch_bounds__(256)
void gemm_bf16(const unsigned short* __restrict__ A,
               const unsigned short* __restrict__ BT,
               const float* __restrict__ bias, void* __restrict__ C,
               int M, int N, int K)
{
    __shared__ __align__(16) unsigned short As[128 * 32];
    __shared__ __align__(16) unsigned short Bs[64 * 32];
    const int tid = threadIdx.x;
    const int l = tid & 63, w = tid >> 6;
    const int l15 = l & 15, l4 = l >> 4;
    const int wm = w >> 1, wn = w & 1;
    const int row0 = blockIdx.y * 128, col0 = blockIdx.x * 64;

    f32x4 acc[4][2];
#pragma unroll
    for (int mi = 0; mi < 4; ++mi)
#pragma unroll
        for (int ni = 0; ni < 2; ++ni) acc[mi][ni] = (f32x4)(0.f);

    for (int k0 = 0; k0 < K; k0 += 32) {
        __syncthreads();
#pragma unroll
        for (int q2 = 0; q2 < 2; ++q2) {
            int o = q2 * 256 + tid;
            int r = o >> 2, pc = o & 3;
            uint4 vv = *(const uint4*)(A + (size_t)(row0 + r) * K + k0 + pc * 8);
            *(uint4*)&As[o * 8] = vv;
        }
        {
            int r = tid >> 2, pc = tid & 3;
            uint4 vv = *(const uint4*)(BT + (size_t)(col0 + r) * K + k0 + pc * 8);
            *(uint4*)&Bs[tid * 8] = vv;
        }
        __syncthreads();

        bf16x8 af[4], bf[2];
#pragma unroll
        for (int mi = 0; mi < 4; ++mi)
            af[mi] = *(bf16x8*)&As[(wm * 64 + mi * 16 + l15) * 32 + l4 * 8];
#pragma unroll
        for (int ni = 0; ni < 2; ++ni)
            bf[ni] = *(bf16x8*)&Bs[(wn * 32 + ni * 16 + l15) * 32 + l4 * 8];
#pragma unroll
        for (int mi = 0; mi < 4; ++mi)
#pragma unroll
            for (int ni = 0; ni < 2; ++ni)
                acc[mi][ni] = __builtin_amdgcn_mfma_f32_16x16x32_bf16(af[mi], bf[ni], acc[mi][ni], 0, 0, 0);
    }

#pragma unroll
    for (int mi = 0; mi < 4; ++mi)
#pragma unroll
        for (int ni = 0; ni < 2; ++ni)
#pragma unroll
            for (int j = 0; j < 4; ++j) {
                int row = row0 + wm * 64 + mi * 16 + l4 * 4 + j;
                int col = col0 + wn * 32 + ni * 16 + l15;
                float vv = acc[mi][ni][j] + bias[col];
                if (BF16OUT)
                    ((unsigned short*)C)[(size_t)row * N + col] = f2bf(vv);
                else
                    ((float*)C)[(size_t)row * N + col] = vv;
            }
}

// ---------------------------------------------------------------------------
// f32 GEMM for vq projection (N=128) — exact, feeds the argmax rescore.
// ---------------------------------------------------------------------------
__global__ __launch_bounds__(256)
void gemm_bias_f32(const float* __restrict__ A, const float* __restrict__ W,
                   const float* __restrict__ bias, float* __restrict__ C,
                   int N, int K)
{
    __shared__ float As[64][20];
    __shared__ float Ws[16][64];
    const int tid = threadIdx.x;
    const int row0 = blockIdx.y * 64, col0 = blockIdx.x * 64;
    const int tr = tid >> 4, tc = tid & 15;
    float acc[4][4] = {};

    for (int k0 = 0; k0 < K; k0 += 16) {
        {
            int r = tid >> 2, c4 = (tid & 3) << 2;
            float4 av = *(const float4*)(A + (size_t)(row0 + r) * K + k0 + c4);
            *(float4*)&As[r][c4] = av;
        }
        {
            int r = tid >> 4, c4 = (tid & 15) << 2;
            float4 wv = *(const float4*)(W + (size_t)(k0 + r) * N + col0 + c4);
            *(float4*)&Ws[r][c4] = wv;
        }
        __syncthreads();
#pragma unroll
        for (int kk = 0; kk < 16; ++kk) {
            float a[4];
#pragma unroll
            for (int i = 0; i < 4; ++i) a[i] = As[tr * 4 + i][kk];
            float4 bv = *(const float4*)&Ws[kk][tc * 4];
            float b[4] = {bv.x, bv.y, bv.z, bv.w};
#pragma unroll
            for (int i = 0; i < 4; ++i)
#pragma unroll
                for (int j = 0; j < 4; ++j)
                    acc[i][j] = fmaf(a[i], b[j], acc[i][j]);
        }
        __syncthreads();
    }
#pragma unroll
    for (int i = 0; i < 4; ++i) {
        int r = row0 + tr * 4 + i;
        int c = col0 + tc * 4;
        float4 ov;
        ov.x = acc[i][0] + bias[c + 0];
        ov.y = acc[i][1] + bias[c + 1];
        ov.z = acc[i][2] + bias[c + 2];
        ov.w = acc[i][3] + bias[c + 3];
        *(float4*)(C + (size_t)r * N + c) = ov;
    }
}

// ---------------------------------------------------------------------------
// Retrieval passes, LDS-staged swapped-MFMA (S^T = K · VQ^T).
// Block: 256 thr = 4 waves; wave w owns q rows [row0+w*16, +16), lane owns
// q = row0+w*16+l15 (one column of S^T -> scalar running max, no shuffles
// in the loop). Grid (Mrows/64, 8 chunks of 1024 keys).
// VQ tile staged once (16KB), K tiles of 64 keys streamed (16KB), both with
// chunk-XOR swizzle (chunk ^ (row&7)) -> conflict-free b128 frag reads.
// PASS 0: per-(row,chunk) bf16 max. PASS 1: push candidates >= thr[row].
// ---------------------------------------------------------------------------
template<int PASS>
__global__ __launch_bounds__(256)
void sim_pass(const unsigned short* __restrict__ vq_hi,
              const unsigned short* __restrict__ vk_hi,
              const float* __restrict__ thr,
              float* __restrict__ pm1,
              unsigned* __restrict__ cnt, unsigned* __restrict__ pairs)
{
    __shared__ __align__(16) unsigned short VQs[64 * 128];
    __shared__ __align__(16) unsigned short Ks[64 * 128];
    const int tid = threadIdx.x;
    const int l = tid & 63, w = tid >> 6;
    const int l15 = l & 15, l4 = l >> 4;
    const int row0 = blockIdx.x * 64;
    const int key0 = blockIdx.y * 1024;
    const int qloc = w * 16 + l15;
    const int q = row0 + qloc;           // this lane's row

    // stage VQ once: 1024 chunks of 16B, source chunk-swizzled, LDS linear
#pragma unroll
    for (int q2 = 0; q2 < 4; ++q2) {
        int oc = q2 * 256 + tid;
        int r = oc >> 4, pc = oc & 15;
        int lc = pc ^ (r & 7);
        uint4 vv = *(const uint4*)(vq_hi + (size_t)(row0 + r) * 128 + lc * 8);
        *(uint4*)&VQs[oc * 8] = vv;
    }
    __syncthreads();
    bf16x8 qf[4];   // B frags: col = q, k = kk*32 + l4*8 + i
#pragma unroll
    for (int kk = 0; kk < 4; ++kk)
        qf[kk] = *(bf16x8*)&VQs[qloc * 128 + (((kk * 4 + l4) ^ (qloc & 7)) * 8)];

    float th = 0.f;
    if (PASS == 1) th = thr[q];
    float vmax = -INFINITY;

    for (int t = 0; t < 16; ++t) {
        __syncthreads();
#pragma unroll
        for (int q2 = 0; q2 < 4; ++q2) {
            int oc = q2 * 256 + tid;
            int r = oc >> 4, pc = oc & 15;
            int lc = pc ^ (r & 7);
            uint4 vv = *(const uint4*)(vk_hi + (size_t)(key0 + t * 64 + r) * 128 + lc * 8);
            *(uint4*)&Ks[oc * 8] = vv;
        }
        __syncthreads();
#pragma unroll
        for (int kb = 0; kb < 4; ++kb) {
            const int key16 = kb * 16 + l15;
            f32x4 s = (f32x4)(0.f);
#pragma unroll
            for (int kk = 0; kk < 4; ++kk) {
                bf16x8 kfr = *(bf16x8*)&Ks[key16 * 128 + (((kk * 4 + l4) ^ (key16 & 7)) * 8)];
                s = __builtin_amdgcn_mfma_f32_16x16x32_bf16(kfr, qf[kk], s, 0, 0, 0);
            }
            // D: row (key) = l4*4 + r, col (q) = l15
            if (PASS == 0) {
#pragma unroll
                for (int r = 0; r < 4; ++r) vmax = fmaxf(vmax, s[r]);
            } else {
#pragma unroll
                for (int r = 0; r < 4; ++r) {
                    if (s[r] >= th) {
                        int key = key0 + t * 64 + kb * 16 + l4 * 4 + r;
                        unsigned slot = atomicAdd(cnt, 1u);
                        if (slot < (unsigned)CAP)
                            pairs[slot] = ((unsigned)q << 13) | (unsigned)key;
                    }
                }
            }
        }
    }
    if (PASS == 0) {
        vmax = fmaxf(vmax, __shfl_xor(vmax, 16));
        vmax = fmaxf(vmax, __shfl_xor(vmax, 32));
        if (l4 == 0) pm1[(size_t)q * 8 + blockIdx.y] = vmax;
    }
}

__global__ void sim_combine(const float* __restrict__ pm1, float* __restrict__ thr)
{
    int r = blockIdx.x * 256 + threadIdx.x;
    if (r >= Mrows) return;
    float m = pm1[r * 8];
#pragma unroll
    for (int c = 1; c < 8; ++c) m = fmaxf(m, pm1[r * 8 + c]);
    thr[r] = m - MARGIN;
}

// ---------------------------------------------------------------------------
// Exact f32 rescore of candidates; first-index argmax via u64 atomicMax.
// enc = flipfloat(sim) << 32 | ~key  (larger = better; ties -> smaller key).
// ---------------------------------------------------------------------------
__global__ __launch_bounds__(256)
void sim_rescore(const unsigned* __restrict__ pairs, const unsigned* __restrict__ cnt,
                 const float* __restrict__ vq, const float* __restrict__ vkeys,
                 unsigned long long* __restrict__ best)
{
    const int l = threadIdx.x & 63;
    const unsigned wav = (blockIdx.x * 256 + threadIdx.x) >> 6;
    const unsigned nw = (gridDim.x * 256) >> 6;
    const unsigned n = min(*cnt, (unsigned)CAP);
    for (unsigned i = wav; i < n; i += nw) {
        unsigned p = pairs[i];
        unsigned row = p >> 13, key = p & 8191u;
        float2 a = *(const float2*)(vq + (size_t)row * 128 + l * 2);
        float2 b = *(const float2*)(vkeys + (size_t)key * 128 + l * 2);
        float d = a.x * b.x + a.y * b.y;
#pragma unroll
        for (int off = 32; off; off >>= 1) d += __shfl_xor(d, off);
        if (l == 0) {
            unsigned fb = __float_as_uint(d);
            fb = (fb & 0x80000000u) ? ~fb : (fb | 0x80000000u);
            unsigned long long enc = ((unsigned long long)fb << 32) | (unsigned)(~key);
            atomicMax(best + row, enc);
        }
    }
}

// ---------------------------------------------------------------------------
// v = hs * v_embed[idx], bf16 out; idx decoded from best[].
// ---------------------------------------------------------------------------
__global__ __launch_bounds__(256)
void build_v_bf16(const float* __restrict__ hs, const float* __restrict__ vembed,
                  const unsigned long long* __restrict__ best,
                  unsigned short* __restrict__ v)
{
    int row = blockIdx.x;
    int id = (int)((~(unsigned)(best[row] & 0xFFFFFFFFull)) & 8191u);
    int c = threadIdx.x * 4;
    float4 a = *(const float4*)(hs + (size_t)row * Dm + c);
    float4 e = *(const float4*)(vembed + (size_t)id * Dm + c);
    uint2 u;
    u.x = (unsigned)f2bf(a.x * e.x) | ((unsigned)f2bf(a.y * e.y) << 16);
    u.y = (unsigned)f2bf(a.z * e.z) | ((unsigned)f2bf(a.w * e.w) << 16);
    *(uint2*)(v + (size_t)row * Dm + c) = u;
}

// ---------------------------------------------------------------------------
// meanv[b][d] = mean over s of v (bf16 in, f32 out) — fully-masked rows.
// ---------------------------------------------------------------------------
__global__ __launch_bounds__(256)
void mean_v_kernel(const unsigned short* __restrict__ v, float* __restrict__ mv)
{
    __shared__ float part[4][64];
    const int d0 = blockIdx.x * 64;
    const int b  = blockIdx.y;
    const int dl = threadIdx.x & 63, jc = threadIdx.x >> 6;
    float s = 0.f;
#pragma unroll 4
    for (int j = jc * 512; j < jc * 512 + 512; ++j)
        s += bf2f(v[((size_t)(b * Ss + j)) * Dm + d0 + dl]);
    part[jc][dl] = s;
    __syncthreads();
    if (threadIdx.x < 64) {
        float t = part[0][dl] + part[1][dl] + part[2][dl] + part[3][dl];
        mv[b * Dm + d0 + dl] = t * (1.f / 2048.f);
    }
}

// ---------------------------------------------------------------------------
// bf16 MFMA flash attention v3 — SWAPPED QK^T (unchanged from R4).
// ---------------------------------------------------------------------------
__global__ __launch_bounds__(256)
void attn_mfma3(const unsigned short* __restrict__ q, const unsigned short* __restrict__ k,
                const unsigned short* __restrict__ v, const float* __restrict__ am,
                const float* __restrict__ dm, const float* __restrict__ meanv,
                unsigned short* __restrict__ o)
{
    __shared__ __align__(16) unsigned char smem[24576];
    __shared__ unsigned char mb[256];
    __shared__ float uniflag[64];
    unsigned char* Ksm = smem;
    unsigned char* Vsm = smem + 8192;
    unsigned char* Psm = smem + 16384;

    const int tid = threadIdx.x;
    const int l = tid & 63, w = tid >> 6;
    const int l15 = l & 15, l4 = l >> 4;
    const int qt = gridDim.x - 1 - blockIdx.x;
    const int h = blockIdx.y, b = blockIdx.z;
    const int row0 = qt * 64;

    {
        unsigned byte = 0;
#pragma unroll
        for (int j = 0; j < 8; ++j) {
            int c = tid * 8 + j;
            byte |= (unsigned)((am[b * Ss + c] * dm[h * Ss + c]) == 0.f) << j;
        }
        mb[tid] = (unsigned char)byte;
    }

    const int qrow = row0 + w * 16 + l15;
    bf16x8 qf[2];
    {
        const unsigned short* qp = q + ((size_t)(b * Ss + qrow)) * Dm + h * HDd + l4 * 8;
        qf[0] = *(const bf16x8*)qp;
        qf[1] = *(const bf16x8*)(qp + 32);
    }

    f32x4 acc[4];
#pragma unroll
    for (int d2 = 0; d2 < 4; ++d2) acc[d2] = (f32x4)(0.f);
    float mrun = -INFINITY, lrun = 0.f;

    for (int kt = 0; kt <= qt; ++kt) {
        __syncthreads();
        {
#pragma unroll
            for (int q2 = 0; q2 < 2; ++q2) {
                int ochunk = q2 * 256 + tid;
                int key = ochunk >> 3, pc = ochunk & 7;
                int lc = pc ^ (key & 7);
                uint4 vv = *(const uint4*)(k + ((size_t)(b * Ss + kt * 64 + key)) * Dm
                                           + h * HDd + lc * 8);
                *(uint4*)&Ksm[ochunk * 16] = vv;
            }
        }
        {
            const unsigned short* vp = v + ((size_t)(b * Ss + kt * 64 + w * 16)) * Dm
                                       + h * HDd + l;
            unsigned vr[8];
#pragma unroll
            for (int j2 = 0; j2 < 8; ++j2) {
                unsigned lo = vp[(size_t)(2 * j2) * Dm];
                unsigned hi = vp[(size_t)(2 * j2 + 1) * Dm];
                vr[j2] = lo | (hi << 16);
            }
            const unsigned swz = (l & 7) << 4;
            uint4 a0; a0.x = vr[0]; a0.y = vr[1]; a0.z = vr[2]; a0.w = vr[3];
            uint4 a1; a1.x = vr[4]; a1.y = vr[5]; a1.z = vr[6]; a1.w = vr[7];
            *(uint4*)&Vsm[l * 128 + ((w * 32) ^ swz)]      = a0;
            *(uint4*)&Vsm[l * 128 + ((w * 32 + 16) ^ swz)] = a1;
        }
        __syncthreads();

        f32x4 sreg[4];
#pragma unroll
        for (int kb = 0; kb < 4; ++kb) {
            const int key16 = kb * 16 + l15;
            const int sw = key16 & 7;
            bf16x8 k0 = *(bf16x8*)&Ksm[key16 * 128 + ((l4 ^ sw) * 16)];
            bf16x8 k1 = *(bf16x8*)&Ksm[key16 * 128 + (((4 + l4) ^ sw) * 16)];
            f32x4 s = (f32x4)(0.f);
            s = __builtin_amdgcn_mfma_f32_16x16x32_bf16(k0, qf[0], s, 0, 0, 0);
            s = __builtin_amdgcn_mfma_f32_16x16x32_bf16(k1, qf[1], s, 0, 0, 0);
            sreg[kb] = s;
        }

        float sv[16];
#pragma unroll
        for (int kb = 0; kb < 4; ++kb)
#pragma unroll
            for (int r = 0; r < 4; ++r) {
                const int key = kt * 64 + kb * 16 + l4 * 4 + r;
                const bool masked = (key > qrow) || ((mb[key >> 3] >> (key & 7)) & 1);
                sv[kb * 4 + r] = sreg[kb][r] * 0.125f + (masked ? MIN_D : 0.f);
            }

        float pm = sv[0];
#pragma unroll
        for (int i = 1; i < 16; ++i) pm = fmaxf(pm, sv[i]);
        pm = fmaxf(pm, __shfl_xor(pm, 16));
        pm = fmaxf(pm, __shfl_xor(pm, 32));
        const float mn = fmaxf(mrun, pm);
        const float sc = __expf(mrun - mn);
        float p[16], rs = 0.f;
#pragma unroll
        for (int i = 0; i < 16; ++i) { p[i] = __expf(sv[i] - mn); rs += p[i]; }
        rs += __shfl_xor(rs, 16);
        rs += __shfl_xor(rs, 32);
        lrun = lrun * sc + rs;
        mrun = mn;
#pragma unroll
        for (int d2 = 0; d2 < 4; ++d2) acc[d2] *= sc;

        const int qloc = w * 16 + l15;
        const unsigned pswz = (l15 & 7) << 4;
#pragma unroll
        for (int kb = 0; kb < 4; ++kb) {
            uint2 u;
            u.x = (unsigned)f2bf(p[kb * 4 + 0]) | ((unsigned)f2bf(p[kb * 4 + 1]) << 16);
            u.y = (unsigned)f2bf(p[kb * 4 + 2]) | ((unsigned)f2bf(p[kb * 4 + 3]) << 16);
            *(uint2*)&Psm[qloc * 128 + ((kb * 32 + l4 * 8) ^ pswz)] = u;
        }

#pragma unroll
        for (int ks = 0; ks < 2; ++ks) {
            bf16x8 pa = *(bf16x8*)&Psm[qloc * 128 + ((ks * 64 + l4 * 16) ^ pswz)];
#pragma unroll
            for (int d2 = 0; d2 < 4; ++d2) {
                const int dd = d2 * 16 + l15;
                bf16x8 vb = *(bf16x8*)&Vsm[dd * 128 + ((ks * 64 + l4 * 16) ^ ((dd & 7) << 4))];
                acc[d2] = __builtin_amdgcn_mfma_f32_16x16x32_bf16(vb, pa, acc[d2], 0, 0, 0);
            }
        }
    }

    const float inv = 1.f / lrun;
    const bool uni = (mrun <= -1e37f);
    __syncthreads();
    float* stage = (float*)smem;
    uniflag[w * 16 + l15] = uni ? 1.f : 0.f;
#pragma unroll
    for (int d2 = 0; d2 < 4; ++d2)
#pragma unroll
        for (int j = 0; j < 4; ++j)
            stage[(w * 16 + l15) * 65 + d2 * 16 + l4 * 4 + j] = acc[d2][j] * inv;
    __syncthreads();
    {
        const int r = tid >> 2, c0 = (tid & 3) * 16;
        const bool u = uniflag[r] != 0.f;
        unsigned short ob[16];
#pragma unroll
        for (int i = 0; i < 16; ++i) {
            float val = u ? meanv[b * Dm + h * HDd + c0 + i] : stage[r * 65 + c0 + i];
            ob[i] = f2bf(val);
        }
        unsigned short* op = o + ((size_t)(b * Ss + row0 + r)) * Dm + h * HDd + c0;
        *(uint4*)op = *(uint4*)&ob[0];
        *(uint4*)(op + 8) = *(uint4*)&ob[8];
    }
}

// ---------------------------------------------------------------------------
extern "C" void kernel_launch(void* const* d_in, const int* in_sizes, int n_in,
                              void* d_out, int out_size, void* d_ws, size_t ws_size,
                              hipStream_t stream)
{
    const float* hs     = (const float*)d_in[0];
    const float* amask  = (const float*)d_in[1];
    const float* Wq     = (const float*)d_in[2];
    const float* bq     = (const float*)d_in[3];
    const float* Wk     = (const float*)d_in[4];
    const float* bk     = (const float*)d_in[5];
    const float* dmask  = (const float*)d_in[6];
    const float* Wvq    = (const float*)d_in[7];
    const float* bvq    = (const float*)d_in[8];
    const float* vkeys  = (const float*)d_in[9];
    const float* vembed = (const float*)d_in[10];
    const float* Wo     = (const float*)d_in[11];
    const float* bo     = (const float*)d_in[12];
    float* out = (float*)d_out;

    char* w = (char*)d_ws;
    size_t off = 0;
    auto take = [&](size_t n) { char* p = w + off; off = (off + n + 255) & ~(size_t)255; return p; };
    unsigned short* hsbf  = (unsigned short*)take((size_t)Mrows * Dm * 2);
    unsigned short* WqT   = (unsigned short*)take((size_t)Dm * Dm * 2);
    unsigned short* WkT   = (unsigned short*)take((size_t)Dm * Dm * 2);
    unsigned short* WoT   = (unsigned short*)take((size_t)Dm * Dm * 2);
    unsigned short* qbf   = (unsigned short*)take((size_t)Mrows * Dm * 2);
    unsigned short* kbf   = (unsigned short*)take((size_t)Mrows * Dm * 2);
    unsigned short* vbuf  = (unsigned short*)take((size_t)Mrows * Dm * 2);
    unsigned short* attno = (unsigned short*)take((size_t)Mrows * Dm * 2);
    float* vqb   = (float*)take((size_t)Mrows * DRr * 4);
    unsigned short* vq_hi = (unsigned short*)take((size_t)Mrows * DRr * 2);
    unsigned short* vk_hi = (unsigned short*)take((size_t)NV * DRr * 2);
    float* pm1   = (float*)take((size_t)Mrows * 8 * 4);
    float* thr   = (float*)take((size_t)Mrows * 4);
    unsigned* cnt = (unsigned*)take(256);
    unsigned* pairs = (unsigned*)take((size_t)CAP * 4);
    unsigned long long* best = (unsigned long long*)take((size_t)Mrows * 8);
    float* mvb   = (float*)take((size_t)Bb * Dm * 4);

    hipMemsetAsync(cnt, 0, 4, stream);
    hipMemsetAsync(best, 0, (size_t)Mrows * 8, stream);

    dim3 blk(256);
    // dtype prep
    cvt_bf16<<<dim3(Mrows * Dm / 2048), blk, 0, stream>>>(hs, hsbf);
    transpose_cvt<<<dim3(Dm / 64, Dm / 64), blk, 0, stream>>>(Wq, WqT, Dm, Dm);
    transpose_cvt<<<dim3(Dm / 64, Dm / 64), blk, 0, stream>>>(Wk, WkT, Dm, Dm);
    transpose_cvt<<<dim3(Dm / 64, Dm / 64), blk, 0, stream>>>(Wo, WoT, Dm, Dm);
    // projections (bf16 MFMA)
    gemm_bf16<true><<<dim3(Dm / 64, Mrows / 128), blk, 0, stream>>>(hsbf, WqT, bq, qbf, Mrows, Dm, Dm);
    gemm_bf16<true><<<dim3(Dm / 64, Mrows / 128), blk, 0, stream>>>(hsbf, WkT, bk, kbf, Mrows, Dm, Dm);
    // retrieval: exact vq, LDS-staged bf16 screen, exact rescore
    gemm_bias_f32<<<dim3(DRr / 64, Mrows / 64), blk, 0, stream>>>(hs, Wvq, bvq, vqb, DRr, Dm);
    cvt_bf16<<<dim3(Mrows * DRr / 2048), blk, 0, stream>>>(vqb, vq_hi);
    cvt_bf16<<<dim3(NV * DRr / 2048), blk, 0, stream>>>(vkeys, vk_hi);
    sim_pass<0><<<dim3(Mrows / 64, 8), blk, 0, stream>>>(vq_hi, vk_hi, nullptr, pm1, nullptr, nullptr);
    sim_combine<<<dim3((Mrows + 255) / 256), blk, 0, stream>>>(pm1, thr);
    sim_pass<1><<<dim3(Mrows / 64, 8), blk, 0, stream>>>(vq_hi, vk_hi, thr, nullptr, cnt, pairs);
    sim_rescore<<<dim3(256), blk, 0, stream>>>(pairs, cnt, vqb, vkeys, best);
    build_v_bf16<<<dim3(Mrows), blk, 0, stream>>>(hs, vembed, best, vbuf);
    mean_v_kernel<<<dim3(Dm / 64, Bb), blk, 0, stream>>>(vbuf, mvb);
    // attention
    attn_mfma3<<<dim3(Ss / 64, Hh, Bb), blk, 0, stream>>>(qbf, kbf, vbuf, amask, dmask, mvb, attno);
    // output projection (f32 out)
    gemm_bf16<false><<<dim3(Dm / 64, Mrows / 128), blk, 0, stream>>>(attno, WoT, bo, out, Mrows, Dm, Dm);
}

// Round 6
// 303.788 us; speedup vs baseline: 1.8642x; 1.3458x over previous
//
#include <hip/hip_runtime.h>
#include <hip/hip_bf16.h>
#include <math.h>

#define MIN_D (-3.402823466e+38f)

constexpr int Bb = 2, Ss = 2048, Dm = 1024, Hh = 16, HDd = 64, NV = 8192, DRr = 128;
constexpr int Mrows = Bb * Ss;   // 4096
constexpr float MARGIN = 0.01f;  // ~22 sigma of bf16 sim error (4.5e-4)
constexpr int CAP = 65536;       // candidate-pair buffer
constexpr float C2 = 0.18033688011112042f;   // 0.125 * log2(e)

typedef __attribute__((ext_vector_type(8))) short bf16x8;
typedef __attribute__((ext_vector_type(4))) float f32x4;

__device__ inline unsigned short f2bf(float x) {
    union { float f; unsigned u; } v; v.f = x;
    unsigned r = v.u + 0x7fff + ((v.u >> 16) & 1);   // RNE
    return (unsigned short)(r >> 16);
}
__device__ inline float bf2f(unsigned short u) {
    union { unsigned u; float f; } v; v.u = ((unsigned)u) << 16;
    return v.f;
}
__device__ inline unsigned pk_bf16(float a, float b) {   // native cvt_pk
    float2 t; t.x = a; t.y = b;
    __hip_bfloat162 h = __float22bfloat162_rn(t);
    return *(unsigned*)&h;
}

// ---------------------------------------------------------------------------
// f32 -> bf16 elementwise. 8 elems/thread; grid = n/2048.
// ---------------------------------------------------------------------------
__global__ __launch_bounds__(256)
void cvt_bf16(const float* __restrict__ x, unsigned short* __restrict__ y)
{
    size_t i = ((size_t)blockIdx.x * 256 + threadIdx.x) * 8;
    float4 a = *(const float4*)(x + i);
    float4 b = *(const float4*)(x + i + 4);
    uint4 p;
    p.x = pk_bf16(a.x, a.y);
    p.y = pk_bf16(a.z, a.w);
    p.z = pk_bf16(b.x, b.y);
    p.w = pk_bf16(b.z, b.w);
    *(uint4*)(y + i) = p;
}

// ---------------------------------------------------------------------------
// Fused transpose+convert of the three 1024x1024 weights (z selects).
// ---------------------------------------------------------------------------
__global__ __launch_bounds__(256)
void transpose_cvt3(const float* __restrict__ W0, const float* __restrict__ W1,
                    const float* __restrict__ W2, unsigned short* __restrict__ T0,
                    unsigned short* __restrict__ T1, unsigned short* __restrict__ T2)
{
    const float* W = blockIdx.z == 0 ? W0 : (blockIdx.z == 1 ? W1 : W2);
    unsigned short* WT = blockIdx.z == 0 ? T0 : (blockIdx.z == 1 ? T1 : T2);
    __shared__ unsigned short T[64][72];
    const int tid = threadIdx.x;
    const int n0 = blockIdx.x * 64, k0 = blockIdx.y * 64;
    const int rr = tid >> 4, cc = tid & 15;
#pragma unroll
    for (int q2 = 0; q2 < 4; ++q2) {
        int kk = rr * 4 + q2;
        float4 v = *(const float4*)(W + (size_t)(k0 + kk) * Dm + n0 + cc * 4);
        T[cc * 4 + 0][kk] = f2bf(v.x);
        T[cc * 4 + 1][kk] = f2bf(v.y);
        T[cc * 4 + 2][kk] = f2bf(v.z);
        T[cc * 4 + 3][kk] = f2bf(v.w);
    }
    __syncthreads();
#pragma unroll
    for (int q2 = 0; q2 < 4; ++q2) {
        int nn = rr * 4 + q2;
        uint2 u;
        u.x = (unsigned)T[nn][cc * 4 + 0] | ((unsigned)T[nn][cc * 4 + 1] << 16);
        u.y = (unsigned)T[nn][cc * 4 + 2] | ((unsigned)T[nn][cc * 4 + 3] << 16);
        *(uint2*)(WT + (size_t)(n0 + nn) * Dm + k0 + cc * 4) = u;
    }
}

// ---------------------------------------------------------------------------
// bf16 MFMA GEMM (dual-target via blockIdx.z): C = A @ BT^T + bias
// ---------------------------------------------------------------------------
template<bool BF16OUT>
__global__ __launch_bounds__(256)
void gemm_bf16(const unsigned short* __restrict__ A,
               const unsigned short* BT0, const unsigned short* BT1,
               const float* bias0, const float* bias1,
               void* C0, void* C1, int N, int K)
{
    const unsigned short* BT = blockIdx.z ? BT1 : BT0;
    const float* bias = blockIdx.z ? bias1 : bias0;
    void* C = blockIdx.z ? C1 : C0;
    __shared__ __align__(16) unsigned short As[128 * 32];
    __shared__ __align__(16) unsigned short Bs[64 * 32];
    const int tid = threadIdx.x;
    const int l = tid & 63, w = tid >> 6;
    const int l15 = l & 15, l4 = l >> 4;
    const int wm = w >> 1, wn = w & 1;
    const int row0 = blockIdx.y * 128, col0 = blockIdx.x * 64;

    f32x4 acc[4][2];
#pragma unroll
    for (int mi = 0; mi < 4; ++mi)
#pragma unroll
        for (int ni = 0; ni < 2; ++ni) acc[mi][ni] = (f32x4)(0.f);

    for (int k0 = 0; k0 < K; k0 += 32) {
        __syncthreads();
#pragma unroll
        for (int q2 = 0; q2 < 2; ++q2) {
            int o = q2 * 256 + tid;
            int r = o >> 2, pc = o & 3;
            uint4 vv = *(const uint4*)(A + (size_t)(row0 + r) * K + k0 + pc * 8);
            *(uint4*)&As[o * 8] = vv;
        }
        {
            int r = tid >> 2, pc = tid & 3;
            uint4 vv = *(const uint4*)(BT + (size_t)(col0 + r) * K + k0 + pc * 8);
            *(uint4*)&Bs[tid * 8] = vv;
        }
        __syncthreads();

        bf16x8 af[4], bf[2];
#pragma unroll
        for (int mi = 0; mi < 4; ++mi)
            af[mi] = *(bf16x8*)&As[(wm * 64 + mi * 16 + l15) * 32 + l4 * 8];
#pragma unroll
        for (int ni = 0; ni < 2; ++ni)
            bf[ni] = *(bf16x8*)&Bs[(wn * 32 + ni * 16 + l15) * 32 + l4 * 8];
#pragma unroll
        for (int mi = 0; mi < 4; ++mi)
#pragma unroll
            for (int ni = 0; ni < 2; ++ni)
                acc[mi][ni] = __builtin_amdgcn_mfma_f32_16x16x32_bf16(af[mi], bf[ni], acc[mi][ni], 0, 0, 0);
    }

#pragma unroll
    for (int mi = 0; mi < 4; ++mi)
#pragma unroll
        for (int ni = 0; ni < 2; ++ni)
#pragma unroll
            for (int j = 0; j < 4; ++j) {
                int row = row0 + wm * 64 + mi * 16 + l4 * 4 + j;
                int col = col0 + wn * 32 + ni * 16 + l15;
                float vv = acc[mi][ni][j] + bias[col];
                if (BF16OUT)
                    ((unsigned short*)C)[(size_t)row * N + col] = f2bf(vv);
                else
                    ((float*)C)[(size_t)row * N + col] = vv;
            }
}

// ---------------------------------------------------------------------------
// f32 GEMM for vq (N=128): exact f32 out + bf16 copy for the screen.
// ---------------------------------------------------------------------------
__global__ __launch_bounds__(256)
void gemm_bias_f32(const float* __restrict__ A, const float* __restrict__ W,
                   const float* __restrict__ bias, float* __restrict__ C,
                   unsigned short* __restrict__ C16, int N, int K)
{
    __shared__ float As[64][20];
    __shared__ float Ws[16][64];
    const int tid = threadIdx.x;
    const int row0 = blockIdx.y * 64, col0 = blockIdx.x * 64;
    const int tr = tid >> 4, tc = tid & 15;
    float acc[4][4] = {};

    for (int k0 = 0; k0 < K; k0 += 16) {
        {
            int r = tid >> 2, c4 = (tid & 3) << 2;
            float4 av = *(const float4*)(A + (size_t)(row0 + r) * K + k0 + c4);
            *(float4*)&As[r][c4] = av;
        }
        {
            int r = tid >> 4, c4 = (tid & 15) << 2;
            float4 wv = *(const float4*)(W + (size_t)(k0 + r) * N + col0 + c4);
            *(float4*)&Ws[r][c4] = wv;
        }
        __syncthreads();
#pragma unroll
        for (int kk = 0; kk < 16; ++kk) {
            float a[4];
#pragma unroll
            for (int i = 0; i < 4; ++i) a[i] = As[tr * 4 + i][kk];
            float4 bv = *(const float4*)&Ws[kk][tc * 4];
            float b[4] = {bv.x, bv.y, bv.z, bv.w};
#pragma unroll
            for (int i = 0; i < 4; ++i)
#pragma unroll
                for (int j = 0; j < 4; ++j)
                    acc[i][j] = fmaf(a[i], b[j], acc[i][j]);
        }
        __syncthreads();
    }
#pragma unroll
    for (int i = 0; i < 4; ++i) {
        int r = row0 + tr * 4 + i;
        int c = col0 + tc * 4;
        float4 ov;
        ov.x = acc[i][0] + bias[c + 0];
        ov.y = acc[i][1] + bias[c + 1];
        ov.z = acc[i][2] + bias[c + 2];
        ov.w = acc[i][3] + bias[c + 3];
        *(float4*)(C + (size_t)r * N + c) = ov;
        uint2 u;
        u.x = pk_bf16(ov.x, ov.y);
        u.y = pk_bf16(ov.z, ov.w);
        *(uint2*)(C16 + (size_t)r * N + c) = u;
    }
}

// ---------------------------------------------------------------------------
// Retrieval screen passes (LDS-staged swapped-MFMA, unchanged core from R5).
// PASS 0: per-(row,chunk) bf16 max -> pm1. PASS 1: inline combine + push.
// ---------------------------------------------------------------------------
template<int PASS>
__global__ __launch_bounds__(256)
void sim_pass(const unsigned short* __restrict__ vq_hi,
              const unsigned short* __restrict__ vk_hi,
              float* __restrict__ pm1,
              unsigned* __restrict__ cnt, unsigned* __restrict__ pairs)
{
    __shared__ __align__(16) unsigned short VQs[64 * 128];
    __shared__ __align__(16) unsigned short Ks[64 * 128];
    __shared__ float thrs[64];
    const int tid = threadIdx.x;
    const int l = tid & 63, w = tid >> 6;
    const int l15 = l & 15, l4 = l >> 4;
    const int row0 = blockIdx.x * 64;
    const int key0 = blockIdx.y * 1024;
    const int qloc = w * 16 + l15;
    const int q = row0 + qloc;

    if (PASS == 1 && tid < 64) {
        const float* pp = pm1 + (size_t)(row0 + tid) * 8;
        float m = pp[0];
#pragma unroll
        for (int c = 1; c < 8; ++c) m = fmaxf(m, pp[c]);
        thrs[tid] = m - MARGIN;
    }
#pragma unroll
    for (int q2 = 0; q2 < 4; ++q2) {
        int oc = q2 * 256 + tid;
        int r = oc >> 4, pc = oc & 15;
        int lc = pc ^ (r & 7);
        uint4 vv = *(const uint4*)(vq_hi + (size_t)(row0 + r) * 128 + lc * 8);
        *(uint4*)&VQs[oc * 8] = vv;
    }
    __syncthreads();
    bf16x8 qf[4];
#pragma unroll
    for (int kk = 0; kk < 4; ++kk)
        qf[kk] = *(bf16x8*)&VQs[qloc * 128 + (((kk * 4 + l4) ^ (qloc & 7)) * 8)];

    float th = (PASS == 1) ? thrs[qloc] : 0.f;
    float vmax = -INFINITY;

    for (int t = 0; t < 16; ++t) {
        __syncthreads();
#pragma unroll
        for (int q2 = 0; q2 < 4; ++q2) {
            int oc = q2 * 256 + tid;
            int r = oc >> 4, pc = oc & 15;
            int lc = pc ^ (r & 7);
            uint4 vv = *(const uint4*)(vk_hi + (size_t)(key0 + t * 64 + r) * 128 + lc * 8);
            *(uint4*)&Ks[oc * 8] = vv;
        }
        __syncthreads();
#pragma unroll
        for (int kb = 0; kb < 4; ++kb) {
            const int key16 = kb * 16 + l15;
            f32x4 s = (f32x4)(0.f);
#pragma unroll
            for (int kk = 0; kk < 4; ++kk) {
                bf16x8 kfr = *(bf16x8*)&Ks[key16 * 128 + (((kk * 4 + l4) ^ (key16 & 7)) * 8)];
                s = __builtin_amdgcn_mfma_f32_16x16x32_bf16(kfr, qf[kk], s, 0, 0, 0);
            }
            if (PASS == 0) {
#pragma unroll
                for (int r = 0; r < 4; ++r) vmax = fmaxf(vmax, s[r]);
            } else {
#pragma unroll
                for (int r = 0; r < 4; ++r) {
                    if (s[r] >= th) {
                        int key = key0 + t * 64 + kb * 16 + l4 * 4 + r;
                        unsigned slot = atomicAdd(cnt, 1u);
                        if (slot < (unsigned)CAP)
                            pairs[slot] = ((unsigned)q << 13) | (unsigned)key;
                    }
                }
            }
        }
    }
    if (PASS == 0) {
        vmax = fmaxf(vmax, __shfl_xor(vmax, 16));
        vmax = fmaxf(vmax, __shfl_xor(vmax, 32));
        if (l4 == 0) pm1[(size_t)q * 8 + blockIdx.y] = vmax;
    }
}

// ---------------------------------------------------------------------------
// Exact f32 rescore; first-index argmax via u64 atomicMax.
// ---------------------------------------------------------------------------
__global__ __launch_bounds__(256)
void sim_rescore(const unsigned* __restrict__ pairs, const unsigned* __restrict__ cnt,
                 const float* __restrict__ vq, const float* __restrict__ vkeys,
                 unsigned long long* __restrict__ best)
{
    const int l = threadIdx.x & 63;
    const unsigned wav = (blockIdx.x * 256 + threadIdx.x) >> 6;
    const unsigned nw = (gridDim.x * 256) >> 6;
    const unsigned n = min(*cnt, (unsigned)CAP);
    for (unsigned i = wav; i < n; i += nw) {
        unsigned p = pairs[i];
        unsigned row = p >> 13, key = p & 8191u;
        float2 a = *(const float2*)(vq + (size_t)row * 128 + l * 2);
        float2 b = *(const float2*)(vkeys + (size_t)key * 128 + l * 2);
        float d = a.x * b.x + a.y * b.y;
#pragma unroll
        for (int off = 32; off; off >>= 1) d += __shfl_xor(d, off);
        if (l == 0) {
            unsigned fb = __float_as_uint(d);
            fb = (fb & 0x80000000u) ? ~fb : (fb | 0x80000000u);
            unsigned long long enc = ((unsigned long long)fb << 32) | (unsigned)(~key);
            atomicMax(best + row, enc);
        }
    }
}

// ---------------------------------------------------------------------------
// Fused build + transpose: VT[(b*16+h)*64 + d][key] = bf16(hs * vembed[idx]).
// Grid (Ss/64 key tiles, B*H). vbuf never materialized.
// ---------------------------------------------------------------------------
__global__ __launch_bounds__(256)
void build_vt(const float* __restrict__ hs, const float* __restrict__ vembed,
              const unsigned long long* __restrict__ best,
              unsigned short* __restrict__ vt)
{
    __shared__ unsigned short T[64][73];
    __shared__ int ids[64];
    const int tid = threadIdx.x;
    const int kt = blockIdx.x;
    const int bh = blockIdx.y;
    const int b = bh >> 4, h = bh & 15;
    if (tid < 64) {
        int row = b * Ss + kt * 64 + tid;
        ids[tid] = (int)((~(unsigned)(best[row] & 0xFFFFFFFFull)) & 8191u);
    }
    __syncthreads();
    {
        int r = tid >> 2, c16 = (tid & 3) * 16;
        size_t hrow = (size_t)(b * Ss + kt * 64 + r) * Dm + h * HDd + c16;
        size_t erow = (size_t)ids[r] * Dm + h * HDd + c16;
#pragma unroll
        for (int q2 = 0; q2 < 4; ++q2) {
            float4 a = *(const float4*)(hs + hrow + q2 * 4);
            float4 e = *(const float4*)(vembed + erow + q2 * 4);
            T[r][c16 + q2 * 4 + 0] = f2bf(a.x * e.x);
            T[r][c16 + q2 * 4 + 1] = f2bf(a.y * e.y);
            T[r][c16 + q2 * 4 + 2] = f2bf(a.z * e.z);
            T[r][c16 + q2 * 4 + 3] = f2bf(a.w * e.w);
        }
    }
    __syncthreads();
    {
        int d = tid >> 2, kc = (tid & 3) * 16;
        unsigned short ob[16];
#pragma unroll
        for (int i = 0; i < 16; ++i) ob[i] = T[kc + i][d];
        unsigned short* op = vt + ((size_t)(b * Hh + h) * HDd + d) * Ss + kt * 64 + kc;
        *(uint4*)op = *(uint4*)&ob[0];
        *(uint4*)(op + 8) = *(uint4*)&ob[8];
    }
}

// ---------------------------------------------------------------------------
// meanv[b][h*64+d] from VT row sums (fully-masked-row substitution value).
// ---------------------------------------------------------------------------
__global__ __launch_bounds__(256)
void mean_vt(const unsigned short* __restrict__ vt, float* __restrict__ mv)
{
    const int bh = blockIdx.x;
    const int b = bh >> 4, h = bh & 15;
    const int d = threadIdx.x >> 2, part = threadIdx.x & 3;
    const unsigned short* row = vt + ((size_t)bh * HDd + d) * Ss + part * 512;
    float s = 0.f;
    for (int j = 0; j < 512; j += 8) {
        uint4 u = *(const uint4*)(row + j);
        const unsigned uu[4] = {u.x, u.y, u.z, u.w};
#pragma unroll
        for (int m = 0; m < 4; ++m) {
            s += bf2f((unsigned short)(uu[m] & 0xffff));
            s += bf2f((unsigned short)(uu[m] >> 16));
        }
    }
    s += __shfl_xor(s, 1);
    s += __shfl_xor(s, 2);
    if (part == 0) mv[b * Dm + h * HDd + d] = s * (1.f / 2048.f);
}

// ---------------------------------------------------------------------------
// bf16 MFMA flash attention v4: QBLK=128 (8 waves), swapped QK^T,
// pre-transposed V, log2-domain softmax + defer-rescale, balanced qt pairing.
// ---------------------------------------------------------------------------
__global__ __launch_bounds__(512)
void attn_mfma4(const unsigned short* __restrict__ q, const unsigned short* __restrict__ k,
                const unsigned short* __restrict__ vt, const float* __restrict__ am,
                const float* __restrict__ dmask, const float* __restrict__ meanv,
                unsigned short* __restrict__ o)
{
    __shared__ __align__(16) unsigned char smem[40960]; // K 8K | VT 8K | P 16K | amdm 8K
    __shared__ float uniflag[128];
    unsigned char* Ksm = smem;
    unsigned char* Vsm = smem + 8192;
    unsigned char* Psm = smem + 16384;
    float* amdmf = (float*)(smem + 32768);

    const int tid = threadIdx.x;
    const int l = tid & 63, w = tid >> 6;
    const int l15 = l & 15, l4 = l >> 4;
    // balanced pairing: CU's two blocks get qt and 15-qt (const 34 tile-steps)
    const int lin = blockIdx.x + (blockIdx.y << 4) + (blockIdx.z << 8);
    const int half = lin >> 8, rem = lin & 255;
    const int qtb = rem & 15;
    const int qt = half ? (15 - qtb) : qtb;
    const int h = rem >> 4;
    const int b = half;
    const int row0 = qt * 128;

    {   // mask table: 0 or MIN_D per key
        int j = tid * 4;
        float4 a = *(const float4*)(am + b * Ss + j);
        float4 d = *(const float4*)(dmask + h * Ss + j);
        float4 m;
        m.x = (a.x * d.x == 0.f) ? MIN_D : 0.f;
        m.y = (a.y * d.y == 0.f) ? MIN_D : 0.f;
        m.z = (a.z * d.z == 0.f) ? MIN_D : 0.f;
        m.w = (a.w * d.w == 0.f) ? MIN_D : 0.f;
        *(float4*)&amdmf[j] = m;
    }

    const int qloc = w * 16 + l15;
    const int qrow = row0 + qloc;
    bf16x8 qf[2];
    {
        const unsigned short* qp = q + ((size_t)(b * Ss + qrow)) * Dm + h * HDd + l4 * 8;
        qf[0] = *(const bf16x8*)qp;
        qf[1] = *(const bf16x8*)(qp + 32);
    }

    f32x4 acc[4];
#pragma unroll
    for (int d2 = 0; d2 < 4; ++d2) acc[d2] = (f32x4)(0.f);
    float mrun = -INFINITY, lrun = 0.f;
    const int ktmax = 2 * qt + 1;

    for (int kt = 0; kt <= ktmax; ++kt) {
        __syncthreads();   // prev tile consumed; covers amdmf at kt=0
        {   // K stage: 512 chunks, source chunk-swizzled, LDS linear
            int key = tid >> 3, pc = tid & 7, lc = pc ^ (key & 7);
            uint4 vv = *(const uint4*)(k + ((size_t)(b * Ss + kt * 64 + key)) * Dm
                                       + h * HDd + lc * 8);
            *(uint4*)&Ksm[tid * 16] = vv;
        }
        {   // VT stage (pre-transposed; K-symmetric)
            int d = tid >> 3, pc = tid & 7, lc = pc ^ (d & 7);
            uint4 vv = *(const uint4*)(vt + ((size_t)(b * Hh + h) * HDd + d) * Ss
                                       + kt * 64 + lc * 8);
            *(uint4*)&Vsm[tid * 16] = vv;
        }
        __syncthreads();

        // S^T = K Q^T
        f32x4 sreg[4];
#pragma unroll
        for (int kb = 0; kb < 4; ++kb) {
            const int key16 = kb * 16 + l15;
            const int sw = key16 & 7;
            bf16x8 k0 = *(bf16x8*)&Ksm[key16 * 128 + ((l4 ^ sw) * 16)];
            bf16x8 k1 = *(bf16x8*)&Ksm[key16 * 128 + (((4 + l4) ^ sw) * 16)];
            f32x4 s = (f32x4)(0.f);
            s = __builtin_amdgcn_mfma_f32_16x16x32_bf16(k0, qf[0], s, 0, 0, 0);
            s = __builtin_amdgcn_mfma_f32_16x16x32_bf16(k1, qf[1], s, 0, 0, 0);
            sreg[kb] = s;
        }

        // log2-domain scores: sv = s*C2 + {0|MIN_D}
        float sv[16];
#pragma unroll
        for (int kb = 0; kb < 4; ++kb)
#pragma unroll
            for (int r = 0; r < 4; ++r) {
                const int key = kt * 64 + kb * 16 + l4 * 4 + r;
                const float mval = (key > qrow) ? MIN_D : amdmf[key];
                sv[kb * 4 + r] = fmaf(sreg[kb][r], C2, mval);
            }

        float pm = fmaxf(fmaxf(sv[0], sv[1]), sv[2]);
        pm = fmaxf(fmaxf(pm, sv[3]), fmaxf(sv[4], sv[5]));
        pm = fmaxf(fmaxf(pm, sv[6]), fmaxf(sv[7], sv[8]));
        pm = fmaxf(fmaxf(pm, sv[9]), fmaxf(sv[10], sv[11]));
        pm = fmaxf(fmaxf(pm, sv[12]), fmaxf(sv[13], sv[14]));
        pm = fmaxf(pm, sv[15]);
        pm = fmaxf(pm, __shfl_xor(pm, 16));
        pm = fmaxf(pm, __shfl_xor(pm, 32));

        // defer-rescale (THR=8 in log2 units -> P bounded by 256)
        if (__any(pm > mrun + 8.f)) {
            const float mn = fmaxf(mrun, pm);
            const float sc = __builtin_amdgcn_exp2f(mrun - mn);
            lrun *= sc;
#pragma unroll
            for (int d2 = 0; d2 < 4; ++d2) acc[d2] *= sc;
            mrun = mn;
        }

        float p[16], rs = 0.f;
#pragma unroll
        for (int i = 0; i < 16; ++i) {
            p[i] = __builtin_amdgcn_exp2f(sv[i] - mrun);
            rs += p[i];
        }
        rs += __shfl_xor(rs, 16);
        rs += __shfl_xor(rs, 32);
        lrun += rs;

        // P store (native cvt_pk, b64 swizzled, wave-private rows)
        const unsigned pswz = (l15 & 7) << 4;
#pragma unroll
        for (int kb = 0; kb < 4; ++kb) {
            uint2 u;
            u.x = pk_bf16(p[kb * 4 + 0], p[kb * 4 + 1]);
            u.y = pk_bf16(p[kb * 4 + 2], p[kb * 4 + 3]);
            *(uint2*)&Psm[qloc * 128 + ((kb * 32 + l4 * 8) ^ pswz)] = u;
        }

        // O^T += V^T P^T (same-wave LDS write->read, in-order)
#pragma unroll
        for (int ks = 0; ks < 2; ++ks) {
            bf16x8 pa = *(bf16x8*)&Psm[qloc * 128 + ((ks * 64 + l4 * 16) ^ pswz)];
#pragma unroll
            for (int d2 = 0; d2 < 4; ++d2) {
                const int dd = d2 * 16 + l15;
                bf16x8 vb = *(bf16x8*)&Vsm[dd * 128 + ((ks * 64 + l4 * 16) ^ ((dd & 7) << 4))];
                acc[d2] = __builtin_amdgcn_mfma_f32_16x16x32_bf16(vb, pa, acc[d2], 0, 0, 0);
            }
        }
    }

    // epilogue: bf16 transpose through LDS, coalesced stores
    const float inv = 1.f / lrun;
    const bool uni = (mrun <= -1e37f);
    __syncthreads();
    unsigned short* stg = (unsigned short*)smem;   // [128][72] bf16 = 18KB
    uniflag[qloc] = uni ? 1.f : 0.f;
#pragma unroll
    for (int d2 = 0; d2 < 4; ++d2) {
        uint2 u;
        u.x = pk_bf16(acc[d2][0] * inv, acc[d2][1] * inv);
        u.y = pk_bf16(acc[d2][2] * inv, acc[d2][3] * inv);
        *(uint2*)&stg[qloc * 72 + d2 * 16 + l4 * 4] = u;
    }
    __syncthreads();
    {
        const int r = tid >> 2, c16 = (tid & 3) * 16;
        const bool u = uniflag[r] != 0.f;
        uint4 o0, o1;
        if (u) {
            unsigned short ob[16];
#pragma unroll
            for (int i = 0; i < 16; ++i)
                ob[i] = f2bf(meanv[b * Dm + h * HDd + c16 + i]);
            o0 = *(uint4*)&ob[0];
            o1 = *(uint4*)&ob[8];
        } else {
            o0 = *(uint4*)&stg[r * 72 + c16];
            o1 = *(uint4*)&stg[r * 72 + c16 + 8];
        }
        unsigned short* op = o + ((size_t)(b * Ss + row0 + r)) * Dm + h * HDd + c16;
        *(uint4*)op = o0;
        *(uint4*)(op + 8) = o1;
    }
}

// ---------------------------------------------------------------------------
extern "C" void kernel_launch(void* const* d_in, const int* in_sizes, int n_in,
                              void* d_out, int out_size, void* d_ws, size_t ws_size,
                              hipStream_t stream)
{
    const float* hs     = (const float*)d_in[0];
    const float* amask  = (const float*)d_in[1];
    const float* Wq     = (const float*)d_in[2];
    const float* bq     = (const float*)d_in[3];
    const float* Wk     = (const float*)d_in[4];
    const float* bk     = (const float*)d_in[5];
    const float* dmask  = (const float*)d_in[6];
    const float* Wvq    = (const float*)d_in[7];
    const float* bvq    = (const float*)d_in[8];
    const float* vkeys  = (const float*)d_in[9];
    const float* vembed = (const float*)d_in[10];
    const float* Wo     = (const float*)d_in[11];
    const float* bo     = (const float*)d_in[12];
    float* out = (float*)d_out;

    char* w = (char*)d_ws;
    size_t off = 0;
    auto take = [&](size_t n) { char* p = w + off; off = (off + n + 255) & ~(size_t)255; return p; };
    unsigned short* hsbf  = (unsigned short*)take((size_t)Mrows * Dm * 2);
    unsigned short* WqT   = (unsigned short*)take((size_t)Dm * Dm * 2);
    unsigned short* WkT   = (unsigned short*)take((size_t)Dm * Dm * 2);
    unsigned short* WoT   = (unsigned short*)take((size_t)Dm * Dm * 2);
    unsigned short* qbf   = (unsigned short*)take((size_t)Mrows * Dm * 2);
    unsigned short* kbf   = (unsigned short*)take((size_t)Mrows * Dm * 2);
    unsigned short* vtb   = (unsigned short*)take((size_t)Mrows * Dm * 2);   // VT
    unsigned short* attno = (unsigned short*)take((size_t)Mrows * Dm * 2);
    float* vqb   = (float*)take((size_t)Mrows * DRr * 4);
    unsigned short* vq_hi = (unsigned short*)take((size_t)Mrows * DRr * 2);
    unsigned short* vk_hi = (unsigned short*)take((size_t)NV * DRr * 2);
    float* pm1   = (float*)take((size_t)Mrows * 8 * 4);
    unsigned* cnt = (unsigned*)take(256);
    unsigned* pairs = (unsigned*)take((size_t)CAP * 4);
    unsigned long long* best = (unsigned long long*)take((size_t)Mrows * 8);
    float* mvb   = (float*)take((size_t)Bb * Dm * 4);

    hipMemsetAsync(cnt, 0, 4, stream);
    hipMemsetAsync(best, 0, (size_t)Mrows * 8, stream);

    dim3 blk(256);
    // dtype prep
    cvt_bf16<<<dim3(Mrows * Dm / 2048), blk, 0, stream>>>(hs, hsbf);
    transpose_cvt3<<<dim3(Dm / 64, Dm / 64, 3), blk, 0, stream>>>(Wq, Wk, Wo, WqT, WkT, WoT);
    // Q,K projections fused via z
    gemm_bf16<true><<<dim3(Dm / 64, Mrows / 128, 2), blk, 0, stream>>>(
        hsbf, WqT, WkT, bq, bk, qbf, kbf, Dm, Dm);
    // retrieval: exact vq (+bf16 copy), screen, exact rescore
    gemm_bias_f32<<<dim3(DRr / 64, Mrows / 64), blk, 0, stream>>>(hs, Wvq, bvq, vqb, vq_hi, DRr, Dm);
    cvt_bf16<<<dim3(NV * DRr / 2048), blk, 0, stream>>>(vkeys, vk_hi);
    sim_pass<0><<<dim3(Mrows / 64, 8), blk, 0, stream>>>(vq_hi, vk_hi, pm1, nullptr, nullptr);
    sim_pass<1><<<dim3(Mrows / 64, 8), blk, 0, stream>>>(vq_hi, vk_hi, pm1, cnt, pairs);
    sim_rescore<<<dim3(256), blk, 0, stream>>>(pairs, cnt, vqb, vkeys, best);
    // fused build+transpose of V, then mean
    build_vt<<<dim3(Ss / 64, Bb * Hh), blk, 0, stream>>>(hs, vembed, best, vtb);
    mean_vt<<<dim3(Bb * Hh), blk, 0, stream>>>(vtb, mvb);
    // attention (512 threads)
    attn_mfma4<<<dim3(Ss / 128, Hh, Bb), dim3(512), 0, stream>>>(
        qbf, kbf, vtb, amask, dmask, mvb, attno);
    // output projection (f32 out)
    gemm_bf16<false><<<dim3(Dm / 64, Mrows / 128, 1), blk, 0, stream>>>(
        attno, WoT, WoT, bo, bo, out, out, Dm, Dm);
}

// Round 7
// 267.150 us; speedup vs baseline: 2.1198x; 1.1371x over previous
//
#include <hip/hip_runtime.h>
#include <hip/hip_bf16.h>
#include <math.h>

#define MIN_D (-3.402823466e+38f)

constexpr int Bb = 2, Ss = 2048, Dm = 1024, Hh = 16, HDd = 64, NV = 8192, DRr = 128;
constexpr int Mrows = Bb * Ss;   // 4096
constexpr float MARGIN = 0.01f;  // ~22 sigma of bf16 sim error (4.5e-4)
constexpr int CAP = 65536;       // candidate-pair buffer
constexpr float C2 = 0.18033688011112042f;   // 0.125 * log2(e)

typedef __attribute__((ext_vector_type(8))) short bf16x8;
typedef __attribute__((ext_vector_type(4))) float f32x4;

__device__ inline unsigned short f2bf(float x) {
    union { float f; unsigned u; } v; v.f = x;
    unsigned r = v.u + 0x7fff + ((v.u >> 16) & 1);   // RNE
    return (unsigned short)(r >> 16);
}
__device__ inline float bf2f(unsigned short u) {
    union { unsigned u; float f; } v; v.u = ((unsigned)u) << 16;
    return v.f;
}
__device__ inline unsigned pk_bf16(float a, float b) {   // native cvt_pk
    float2 t; t.x = a; t.y = b;
    __hip_bfloat162 h = __float22bfloat162_rn(t);
    return *(unsigned*)&h;
}

// ---------------------------------------------------------------------------
// f32 -> bf16 elementwise. 8 elems/thread; grid = n/2048.
// ---------------------------------------------------------------------------
__global__ __launch_bounds__(256)
void cvt_bf16(const float* __restrict__ x, unsigned short* __restrict__ y)
{
    size_t i = ((size_t)blockIdx.x * 256 + threadIdx.x) * 8;
    float4 a = *(const float4*)(x + i);
    float4 b = *(const float4*)(x + i + 4);
    uint4 p;
    p.x = pk_bf16(a.x, a.y);
    p.y = pk_bf16(a.z, a.w);
    p.z = pk_bf16(b.x, b.y);
    p.w = pk_bf16(b.z, b.w);
    *(uint4*)(y + i) = p;
}

// ---------------------------------------------------------------------------
// Fused transpose+convert of the three 1024x1024 weights (z selects).
// ---------------------------------------------------------------------------
__global__ __launch_bounds__(256)
void transpose_cvt3(const float* __restrict__ W0, const float* __restrict__ W1,
                    const float* __restrict__ W2, unsigned short* __restrict__ T0,
                    unsigned short* __restrict__ T1, unsigned short* __restrict__ T2)
{
    const float* W = blockIdx.z == 0 ? W0 : (blockIdx.z == 1 ? W1 : W2);
    unsigned short* WT = blockIdx.z == 0 ? T0 : (blockIdx.z == 1 ? T1 : T2);
    __shared__ unsigned short T[64][72];
    const int tid = threadIdx.x;
    const int n0 = blockIdx.x * 64, k0 = blockIdx.y * 64;
    const int rr = tid >> 4, cc = tid & 15;
#pragma unroll
    for (int q2 = 0; q2 < 4; ++q2) {
        int kk = rr * 4 + q2;
        float4 v = *(const float4*)(W + (size_t)(k0 + kk) * Dm + n0 + cc * 4);
        T[cc * 4 + 0][kk] = f2bf(v.x);
        T[cc * 4 + 1][kk] = f2bf(v.y);
        T[cc * 4 + 2][kk] = f2bf(v.z);
        T[cc * 4 + 3][kk] = f2bf(v.w);
    }
    __syncthreads();
#pragma unroll
    for (int q2 = 0; q2 < 4; ++q2) {
        int nn = rr * 4 + q2;
        uint2 u;
        u.x = (unsigned)T[nn][cc * 4 + 0] | ((unsigned)T[nn][cc * 4 + 1] << 16);
        u.y = (unsigned)T[nn][cc * 4 + 2] | ((unsigned)T[nn][cc * 4 + 3] << 16);
        *(uint2*)(WT + (size_t)(n0 + nn) * Dm + k0 + cc * 4) = u;
    }
}

// ---------------------------------------------------------------------------
// bf16 MFMA GEMM, 128x128 tile, 512 thr = 8 waves (2m x 4n), BK=32.
// Dual-target via blockIdx.z. Same verified frag addressing as before.
// ---------------------------------------------------------------------------
template<bool BF16OUT>
__global__ __launch_bounds__(512)
void gemm_bf16(const unsigned short* __restrict__ A,
               const unsigned short* BT0, const unsigned short* BT1,
               const float* bias0, const float* bias1,
               void* C0, void* C1, int N, int K)
{
    const unsigned short* BT = blockIdx.z ? BT1 : BT0;
    const float* bias = blockIdx.z ? bias1 : bias0;
    void* C = blockIdx.z ? C1 : C0;
    __shared__ __align__(16) unsigned short As[128 * 32];
    __shared__ __align__(16) unsigned short Bs[128 * 32];
    const int tid = threadIdx.x;
    const int l = tid & 63, w = tid >> 6;
    const int l15 = l & 15, l4 = l >> 4;
    const int wm = w >> 2, wn = w & 3;           // 2 x 4 wave grid
    const int row0 = blockIdx.y * 128, col0 = blockIdx.x * 128;

    f32x4 acc[4][2];
#pragma unroll
    for (int mi = 0; mi < 4; ++mi)
#pragma unroll
        for (int ni = 0; ni < 2; ++ni) acc[mi][ni] = (f32x4)(0.f);

    for (int k0 = 0; k0 < K; k0 += 32) {
        __syncthreads();
        {   // A tile: 512 chunks of 16B, 1/thread
            int r = tid >> 2, pc = tid & 3;
            uint4 vv = *(const uint4*)(A + (size_t)(row0 + r) * K + k0 + pc * 8);
            *(uint4*)&As[tid * 8] = vv;
        }
        {   // B tile: 512 chunks
            int r = tid >> 2, pc = tid & 3;
            uint4 vv = *(const uint4*)(BT + (size_t)(col0 + r) * K + k0 + pc * 8);
            *(uint4*)&Bs[tid * 8] = vv;
        }
        __syncthreads();

        bf16x8 af[4], bf[2];
#pragma unroll
        for (int mi = 0; mi < 4; ++mi)
            af[mi] = *(bf16x8*)&As[(wm * 64 + mi * 16 + l15) * 32 + l4 * 8];
#pragma unroll
        for (int ni = 0; ni < 2; ++ni)
            bf[ni] = *(bf16x8*)&Bs[(wn * 32 + ni * 16 + l15) * 32 + l4 * 8];
#pragma unroll
        for (int mi = 0; mi < 4; ++mi)
#pragma unroll
            for (int ni = 0; ni < 2; ++ni)
                acc[mi][ni] = __builtin_amdgcn_mfma_f32_16x16x32_bf16(af[mi], bf[ni], acc[mi][ni], 0, 0, 0);
    }

#pragma unroll
    for (int mi = 0; mi < 4; ++mi)
#pragma unroll
        for (int ni = 0; ni < 2; ++ni)
#pragma unroll
            for (int j = 0; j < 4; ++j) {
                int row = row0 + wm * 64 + mi * 16 + l4 * 4 + j;
                int col = col0 + wn * 32 + ni * 16 + l15;
                float vv = acc[mi][ni][j] + bias[col];
                if (BF16OUT)
                    ((unsigned short*)C)[(size_t)row * N + col] = f2bf(vv);
                else
                    ((float*)C)[(size_t)row * N + col] = vv;
            }
}

// ---------------------------------------------------------------------------
// Split-K f32 GEMM for vq: partial[z] = A[:, z*256:(z+1)*256] @ W-slice.
// Grid (2, 64, 4) = 512 blocks; BK=32, 8 iters. No bias (added in reduce).
// ---------------------------------------------------------------------------
__global__ __launch_bounds__(256)
void gemm_vq_partial(const float* __restrict__ A, const float* __restrict__ W,
                     float* __restrict__ P)
{
    __shared__ float As[64][36];
    __shared__ float Ws[32][64];
    const int tid = threadIdx.x;
    const int row0 = blockIdx.y * 64, col0 = blockIdx.x * 64;
    const int kbase = blockIdx.z * 256;
    const int tr = tid >> 4, tc = tid & 15;
    float acc[4][4] = {};

    for (int k0 = kbase; k0 < kbase + 256; k0 += 32) {
        __syncthreads();
#pragma unroll
        for (int q2 = 0; q2 < 2; ++q2) {   // A: 64x32 f32 = 512 float4
            int oc = q2 * 256 + tid;
            int r = oc >> 3, c4 = (oc & 7) << 2;
            *(float4*)&As[r][c4] = *(const float4*)(A + (size_t)(row0 + r) * Dm + k0 + c4);
        }
#pragma unroll
        for (int q2 = 0; q2 < 2; ++q2) {   // W: 32x64 f32 = 512 float4
            int oc = q2 * 256 + tid;
            int r = oc >> 4, c4 = (oc & 15) << 2;
            *(float4*)&Ws[r][c4] = *(const float4*)(W + (size_t)(k0 + r) * DRr + col0 + c4);
        }
        __syncthreads();
#pragma unroll 8
        for (int kk = 0; kk < 32; ++kk) {
            float a[4];
#pragma unroll
            for (int i = 0; i < 4; ++i) a[i] = As[tr * 4 + i][kk];
            float4 bv = *(const float4*)&Ws[kk][tc * 4];
            float b[4] = {bv.x, bv.y, bv.z, bv.w};
#pragma unroll
            for (int i = 0; i < 4; ++i)
#pragma unroll
                for (int j = 0; j < 4; ++j)
                    acc[i][j] = fmaf(a[i], b[j], acc[i][j]);
        }
    }
    float* Pz = P + (size_t)blockIdx.z * Mrows * DRr;
#pragma unroll
    for (int i = 0; i < 4; ++i) {
        int r = row0 + tr * 4 + i;
        float4 ov = {acc[i][0], acc[i][1], acc[i][2], acc[i][3]};
        *(float4*)(Pz + (size_t)r * DRr + col0 + tc * 4) = ov;
    }
}

// ---------------------------------------------------------------------------
// Reduce split-K partials (fixed order) + bias -> vqb f32 and vq_hi bf16.
// ---------------------------------------------------------------------------
__global__ __launch_bounds__(256)
void reduce_vq(const float* __restrict__ P, const float* __restrict__ bias,
               float* __restrict__ vqb, unsigned short* __restrict__ vq_hi)
{
    const size_t i4 = ((size_t)blockIdx.x * 256 + threadIdx.x) * 4;
    const int col = (int)(i4 & 127);
    const size_t stride = (size_t)Mrows * DRr;
    float4 s = *(const float4*)(P + i4);
#pragma unroll
    for (int z = 1; z < 4; ++z) {
        float4 p = *(const float4*)(P + stride * z + i4);
        s.x += p.x; s.y += p.y; s.z += p.z; s.w += p.w;
    }
    float4 bv = *(const float4*)(bias + col);
    s.x += bv.x; s.y += bv.y; s.z += bv.z; s.w += bv.w;
    *(float4*)(vqb + i4) = s;
    uint2 u;
    u.x = pk_bf16(s.x, s.y);
    u.y = pk_bf16(s.z, s.w);
    *(uint2*)(vq_hi + i4) = u;
}

// ---------------------------------------------------------------------------
// Retrieval screen passes (LDS-staged swapped-MFMA).
// PASS 0: per-(row,chunk) bf16 max -> pm1. PASS 1: inline combine + push.
// ---------------------------------------------------------------------------
template<int PASS>
__global__ __launch_bounds__(256)
void sim_pass(const unsigned short* __restrict__ vq_hi,
              const unsigned short* __restrict__ vk_hi,
              float* __restrict__ pm1,
              unsigned* __restrict__ cnt, unsigned* __restrict__ pairs)
{
    __shared__ __align__(16) unsigned short VQs[64 * 128];
    __shared__ __align__(16) unsigned short Ks[64 * 128];
    __shared__ float thrs[64];
    const int tid = threadIdx.x;
    const int l = tid & 63, w = tid >> 6;
    const int l15 = l & 15, l4 = l >> 4;
    const int row0 = blockIdx.x * 64;
    const int key0 = blockIdx.y * 1024;
    const int qloc = w * 16 + l15;
    const int q = row0 + qloc;

    if (PASS == 1 && tid < 64) {
        const float* pp = pm1 + (size_t)(row0 + tid) * 8;
        float m = pp[0];
#pragma unroll
        for (int c = 1; c < 8; ++c) m = fmaxf(m, pp[c]);
        thrs[tid] = m - MARGIN;
    }
#pragma unroll
    for (int q2 = 0; q2 < 4; ++q2) {
        int oc = q2 * 256 + tid;
        int r = oc >> 4, pc = oc & 15;
        int lc = pc ^ (r & 7);
        uint4 vv = *(const uint4*)(vq_hi + (size_t)(row0 + r) * 128 + lc * 8);
        *(uint4*)&VQs[oc * 8] = vv;
    }
    __syncthreads();
    bf16x8 qf[4];
#pragma unroll
    for (int kk = 0; kk < 4; ++kk)
        qf[kk] = *(bf16x8*)&VQs[qloc * 128 + (((kk * 4 + l4) ^ (qloc & 7)) * 8)];

    float th = (PASS == 1) ? thrs[qloc] : 0.f;
    float vmax = -INFINITY;

    for (int t = 0; t < 16; ++t) {
        __syncthreads();
#pragma unroll
        for (int q2 = 0; q2 < 4; ++q2) {
            int oc = q2 * 256 + tid;
            int r = oc >> 4, pc = oc & 15;
            int lc = pc ^ (r & 7);
            uint4 vv = *(const uint4*)(vk_hi + (size_t)(key0 + t * 64 + r) * 128 + lc * 8);
            *(uint4*)&Ks[oc * 8] = vv;
        }
        __syncthreads();
#pragma unroll
        for (int kb = 0; kb < 4; ++kb) {
            const int key16 = kb * 16 + l15;
            f32x4 s = (f32x4)(0.f);
#pragma unroll
            for (int kk = 0; kk < 4; ++kk) {
                bf16x8 kfr = *(bf16x8*)&Ks[key16 * 128 + (((kk * 4 + l4) ^ (key16 & 7)) * 8)];
                s = __builtin_amdgcn_mfma_f32_16x16x32_bf16(kfr, qf[kk], s, 0, 0, 0);
            }
            if (PASS == 0) {
#pragma unroll
                for (int r = 0; r < 4; ++r) vmax = fmaxf(vmax, s[r]);
            } else {
#pragma unroll
                for (int r = 0; r < 4; ++r) {
                    if (s[r] >= th) {
                        int key = key0 + t * 64 + kb * 16 + l4 * 4 + r;
                        unsigned slot = atomicAdd(cnt, 1u);
                        if (slot < (unsigned)CAP)
                            pairs[slot] = ((unsigned)q << 13) | (unsigned)key;
                    }
                }
            }
        }
    }
    if (PASS == 0) {
        vmax = fmaxf(vmax, __shfl_xor(vmax, 16));
        vmax = fmaxf(vmax, __shfl_xor(vmax, 32));
        if (l4 == 0) pm1[(size_t)q * 8 + blockIdx.y] = vmax;
    }
}

// ---------------------------------------------------------------------------
// Exact f32 rescore; first-index argmax via u64 atomicMax.
// ---------------------------------------------------------------------------
__global__ __launch_bounds__(256)
void sim_rescore(const unsigned* __restrict__ pairs, const unsigned* __restrict__ cnt,
                 const float* __restrict__ vq, const float* __restrict__ vkeys,
                 unsigned long long* __restrict__ best)
{
    const int l = threadIdx.x & 63;
    const unsigned wav = (blockIdx.x * 256 + threadIdx.x) >> 6;
    const unsigned nw = (gridDim.x * 256) >> 6;
    const unsigned n = min(*cnt, (unsigned)CAP);
    for (unsigned i = wav; i < n; i += nw) {
        unsigned p = pairs[i];
        unsigned row = p >> 13, key = p & 8191u;
        float2 a = *(const float2*)(vq + (size_t)row * 128 + l * 2);
        float2 b = *(const float2*)(vkeys + (size_t)key * 128 + l * 2);
        float d = a.x * b.x + a.y * b.y;
#pragma unroll
        for (int off = 32; off; off >>= 1) d += __shfl_xor(d, off);
        if (l == 0) {
            unsigned fb = __float_as_uint(d);
            fb = (fb & 0x80000000u) ? ~fb : (fb | 0x80000000u);
            unsigned long long enc = ((unsigned long long)fb << 32) | (unsigned)(~key);
            atomicMax(best + row, enc);
        }
    }
}

// ---------------------------------------------------------------------------
// Fused build + transpose: VT[(b*16+h)*64 + d][key] = bf16(hs * vembed[idx]).
// ---------------------------------------------------------------------------
__global__ __launch_bounds__(256)
void build_vt(const float* __restrict__ hs, const float* __restrict__ vembed,
              const unsigned long long* __restrict__ best,
              unsigned short* __restrict__ vt)
{
    __shared__ unsigned short T[64][73];
    __shared__ int ids[64];
    const int tid = threadIdx.x;
    const int kt = blockIdx.x;
    const int bh = blockIdx.y;
    const int b = bh >> 4, h = bh & 15;
    if (tid < 64) {
        int row = b * Ss + kt * 64 + tid;
        ids[tid] = (int)((~(unsigned)(best[row] & 0xFFFFFFFFull)) & 8191u);
    }
    __syncthreads();
    {
        int r = tid >> 2, c16 = (tid & 3) * 16;
        size_t hrow = (size_t)(b * Ss + kt * 64 + r) * Dm + h * HDd + c16;
        size_t erow = (size_t)ids[r] * Dm + h * HDd + c16;
#pragma unroll
        for (int q2 = 0; q2 < 4; ++q2) {
            float4 a = *(const float4*)(hs + hrow + q2 * 4);
            float4 e = *(const float4*)(vembed + erow + q2 * 4);
            T[r][c16 + q2 * 4 + 0] = f2bf(a.x * e.x);
            T[r][c16 + q2 * 4 + 1] = f2bf(a.y * e.y);
            T[r][c16 + q2 * 4 + 2] = f2bf(a.z * e.z);
            T[r][c16 + q2 * 4 + 3] = f2bf(a.w * e.w);
        }
    }
    __syncthreads();
    {
        int d = tid >> 2, kc = (tid & 3) * 16;
        unsigned short ob[16];
#pragma unroll
        for (int i = 0; i < 16; ++i) ob[i] = T[kc + i][d];
        unsigned short* op = vt + ((size_t)(b * Hh + h) * HDd + d) * Ss + kt * 64 + kc;
        *(uint4*)op = *(uint4*)&ob[0];
        *(uint4*)(op + 8) = *(uint4*)&ob[8];
    }
}

// ---------------------------------------------------------------------------
// meanv[b][h*64+d] from VT row sums (fully-masked-row substitution value).
// ---------------------------------------------------------------------------
__global__ __launch_bounds__(256)
void mean_vt(const unsigned short* __restrict__ vt, float* __restrict__ mv)
{
    const int bh = blockIdx.x;
    const int b = bh >> 4, h = bh & 15;
    const int d = threadIdx.x >> 2, part = threadIdx.x & 3;
    const unsigned short* row = vt + ((size_t)bh * HDd + d) * Ss + part * 512;
    float s = 0.f;
    for (int j = 0; j < 512; j += 8) {
        uint4 u = *(const uint4*)(row + j);
        const unsigned uu[4] = {u.x, u.y, u.z, u.w};
#pragma unroll
        for (int m = 0; m < 4; ++m) {
            s += bf2f((unsigned short)(uu[m] & 0xffff));
            s += bf2f((unsigned short)(uu[m] >> 16));
        }
    }
    s += __shfl_xor(s, 1);
    s += __shfl_xor(s, 2);
    if (part == 0) mv[b * Dm + h * HDd + d] = s * (1.f / 2048.f);
}

// ---------------------------------------------------------------------------
// bf16 MFMA flash attention v4 (unchanged from R6): QBLK=128/8 waves,
// swapped QK^T, pre-transposed V, log2 softmax + defer-rescale, balanced qt.
// ---------------------------------------------------------------------------
__global__ __launch_bounds__(512)
void attn_mfma4(const unsigned short* __restrict__ q, const unsigned short* __restrict__ k,
                const unsigned short* __restrict__ vt, const float* __restrict__ am,
                const float* __restrict__ dmask, const float* __restrict__ meanv,
                unsigned short* __restrict__ o)
{
    __shared__ __align__(16) unsigned char smem[40960]; // K 8K | VT 8K | P 16K | amdm 8K
    __shared__ float uniflag[128];
    unsigned char* Ksm = smem;
    unsigned char* Vsm = smem + 8192;
    unsigned char* Psm = smem + 16384;
    float* amdmf = (float*)(smem + 32768);

    const int tid = threadIdx.x;
    const int l = tid & 63, w = tid >> 6;
    const int l15 = l & 15, l4 = l >> 4;
    const int lin = blockIdx.x + (blockIdx.y << 4) + (blockIdx.z << 8);
    const int half = lin >> 8, rem = lin & 255;
    const int qtb = rem & 15;
    const int qt = half ? (15 - qtb) : qtb;
    const int h = rem >> 4;
    const int b = half;
    const int row0 = qt * 128;

    {
        int j = tid * 4;
        float4 a = *(const float4*)(am + b * Ss + j);
        float4 d = *(const float4*)(dmask + h * Ss + j);
        float4 m;
        m.x = (a.x * d.x == 0.f) ? MIN_D : 0.f;
        m.y = (a.y * d.y == 0.f) ? MIN_D : 0.f;
        m.z = (a.z * d.z == 0.f) ? MIN_D : 0.f;
        m.w = (a.w * d.w == 0.f) ? MIN_D : 0.f;
        *(float4*)&amdmf[j] = m;
    }

    const int qloc = w * 16 + l15;
    const int qrow = row0 + qloc;
    bf16x8 qf[2];
    {
        const unsigned short* qp = q + ((size_t)(b * Ss + qrow)) * Dm + h * HDd + l4 * 8;
        qf[0] = *(const bf16x8*)qp;
        qf[1] = *(const bf16x8*)(qp + 32);
    }

    f32x4 acc[4];
#pragma unroll
    for (int d2 = 0; d2 < 4; ++d2) acc[d2] = (f32x4)(0.f);
    float mrun = -INFINITY, lrun = 0.f;
    const int ktmax = 2 * qt + 1;

    for (int kt = 0; kt <= ktmax; ++kt) {
        __syncthreads();
        {
            int key = tid >> 3, pc = tid & 7, lc = pc ^ (key & 7);
            uint4 vv = *(const uint4*)(k + ((size_t)(b * Ss + kt * 64 + key)) * Dm
                                       + h * HDd + lc * 8);
            *(uint4*)&Ksm[tid * 16] = vv;
        }
        {
            int d = tid >> 3, pc = tid & 7, lc = pc ^ (d & 7);
            uint4 vv = *(const uint4*)(vt + ((size_t)(b * Hh + h) * HDd + d) * Ss
                                       + kt * 64 + lc * 8);
            *(uint4*)&Vsm[tid * 16] = vv;
        }
        __syncthreads();

        f32x4 sreg[4];
#pragma unroll
        for (int kb = 0; kb < 4; ++kb) {
            const int key16 = kb * 16 + l15;
            const int sw = key16 & 7;
            bf16x8 k0 = *(bf16x8*)&Ksm[key16 * 128 + ((l4 ^ sw) * 16)];
            bf16x8 k1 = *(bf16x8*)&Ksm[key16 * 128 + (((4 + l4) ^ sw) * 16)];
            f32x4 s = (f32x4)(0.f);
            s = __builtin_amdgcn_mfma_f32_16x16x32_bf16(k0, qf[0], s, 0, 0, 0);
            s = __builtin_amdgcn_mfma_f32_16x16x32_bf16(k1, qf[1], s, 0, 0, 0);
            sreg[kb] = s;
        }

        float sv[16];
#pragma unroll
        for (int kb = 0; kb < 4; ++kb)
#pragma unroll
            for (int r = 0; r < 4; ++r) {
                const int key = kt * 64 + kb * 16 + l4 * 4 + r;
                const float mval = (key > qrow) ? MIN_D : amdmf[key];
                sv[kb * 4 + r] = fmaf(sreg[kb][r], C2, mval);
            }

        float pm = fmaxf(fmaxf(sv[0], sv[1]), sv[2]);
        pm = fmaxf(fmaxf(pm, sv[3]), fmaxf(sv[4], sv[5]));
        pm = fmaxf(fmaxf(pm, sv[6]), fmaxf(sv[7], sv[8]));
        pm = fmaxf(fmaxf(pm, sv[9]), fmaxf(sv[10], sv[11]));
        pm = fmaxf(fmaxf(pm, sv[12]), fmaxf(sv[13], sv[14]));
        pm = fmaxf(pm, sv[15]);
        pm = fmaxf(pm, __shfl_xor(pm, 16));
        pm = fmaxf(pm, __shfl_xor(pm, 32));

        if (__any(pm > mrun + 8.f)) {
            const float mn = fmaxf(mrun, pm);
            const float sc = __builtin_amdgcn_exp2f(mrun - mn);
            lrun *= sc;
#pragma unroll
            for (int d2 = 0; d2 < 4; ++d2) acc[d2] *= sc;
            mrun = mn;
        }

        float p[16], rs = 0.f;
#pragma unroll
        for (int i = 0; i < 16; ++i) {
            p[i] = __builtin_amdgcn_exp2f(sv[i] - mrun);
            rs += p[i];
        }
        rs += __shfl_xor(rs, 16);
        rs += __shfl_xor(rs, 32);
        lrun += rs;

        const unsigned pswz = (l15 & 7) << 4;
#pragma unroll
        for (int kb = 0; kb < 4; ++kb) {
            uint2 u;
            u.x = pk_bf16(p[kb * 4 + 0], p[kb * 4 + 1]);
            u.y = pk_bf16(p[kb * 4 + 2], p[kb * 4 + 3]);
            *(uint2*)&Psm[qloc * 128 + ((kb * 32 + l4 * 8) ^ pswz)] = u;
        }

#pragma unroll
        for (int ks = 0; ks < 2; ++ks) {
            bf16x8 pa = *(bf16x8*)&Psm[qloc * 128 + ((ks * 64 + l4 * 16) ^ pswz)];
#pragma unroll
            for (int d2 = 0; d2 < 4; ++d2) {
                const int dd = d2 * 16 + l15;
                bf16x8 vb = *(bf16x8*)&Vsm[dd * 128 + ((ks * 64 + l4 * 16) ^ ((dd & 7) << 4))];
                acc[d2] = __builtin_amdgcn_mfma_f32_16x16x32_bf16(vb, pa, acc[d2], 0, 0, 0);
            }
        }
    }

    const float inv = 1.f / lrun;
    const bool uni = (mrun <= -1e37f);
    __syncthreads();
    unsigned short* stg = (unsigned short*)smem;
    uniflag[qloc] = uni ? 1.f : 0.f;
#pragma unroll
    for (int d2 = 0; d2 < 4; ++d2) {
        uint2 u;
        u.x = pk_bf16(acc[d2][0] * inv, acc[d2][1] * inv);
        u.y = pk_bf16(acc[d2][2] * inv, acc[d2][3] * inv);
        *(uint2*)&stg[qloc * 72 + d2 * 16 + l4 * 4] = u;
    }
    __syncthreads();
    {
        const int r = tid >> 2, c16 = (tid & 3) * 16;
        const bool u = uniflag[r] != 0.f;
        uint4 o0, o1;
        if (u) {
            unsigned short ob[16];
#pragma unroll
            for (int i = 0; i < 16; ++i)
                ob[i] = f2bf(meanv[b * Dm + h * HDd + c16 + i]);
            o0 = *(uint4*)&ob[0];
            o1 = *(uint4*)&ob[8];
        } else {
            o0 = *(uint4*)&stg[r * 72 + c16];
            o1 = *(uint4*)&stg[r * 72 + c16 + 8];
        }
        unsigned short* op = o + ((size_t)(b * Ss + row0 + r)) * Dm + h * HDd + c16;
        *(uint4*)op = o0;
        *(uint4*)(op + 8) = o1;
    }
}

// ---------------------------------------------------------------------------
extern "C" void kernel_launch(void* const* d_in, const int* in_sizes, int n_in,
                              void* d_out, int out_size, void* d_ws, size_t ws_size,
                              hipStream_t stream)
{
    const float* hs     = (const float*)d_in[0];
    const float* amask  = (const float*)d_in[1];
    const float* Wq     = (const float*)d_in[2];
    const float* bq     = (const float*)d_in[3];
    const float* Wk     = (const float*)d_in[4];
    const float* bk     = (const float*)d_in[5];
    const float* dmask  = (const float*)d_in[6];
    const float* Wvq    = (const float*)d_in[7];
    const float* bvq    = (const float*)d_in[8];
    const float* vkeys  = (const float*)d_in[9];
    const float* vembed = (const float*)d_in[10];
    const float* Wo     = (const float*)d_in[11];
    const float* bo     = (const float*)d_in[12];
    float* out = (float*)d_out;

    char* w = (char*)d_ws;
    size_t off = 0;
    auto take = [&](size_t n) { char* p = w + off; off = (off + n + 255) & ~(size_t)255; return p; };
    unsigned short* hsbf  = (unsigned short*)take((size_t)Mrows * Dm * 2);
    unsigned short* WqT   = (unsigned short*)take((size_t)Dm * Dm * 2);
    unsigned short* WkT   = (unsigned short*)take((size_t)Dm * Dm * 2);
    unsigned short* WoT   = (unsigned short*)take((size_t)Dm * Dm * 2);
    unsigned short* qbf   = (unsigned short*)take((size_t)Mrows * Dm * 2);
    unsigned short* kbf   = (unsigned short*)take((size_t)Mrows * Dm * 2);
    unsigned short* vtb   = (unsigned short*)take((size_t)Mrows * Dm * 2);   // VT
    unsigned short* attno = (unsigned short*)take((size_t)Mrows * Dm * 2);
    float* vqp   = (float*)take((size_t)4 * Mrows * DRr * 4);               // split-K partials
    float* vqb   = (float*)take((size_t)Mrows * DRr * 4);
    unsigned short* vq_hi = (unsigned short*)take((size_t)Mrows * DRr * 2);
    unsigned short* vk_hi = (unsigned short*)take((size_t)NV * DRr * 2);
    float* pm1   = (float*)take((size_t)Mrows * 8 * 4);
    unsigned* cnt = (unsigned*)take(256);
    unsigned* pairs = (unsigned*)take((size_t)CAP * 4);
    unsigned long long* best = (unsigned long long*)take((size_t)Mrows * 8);
    float* mvb   = (float*)take((size_t)Bb * Dm * 4);

    hipMemsetAsync(cnt, 0, 4, stream);
    hipMemsetAsync(best, 0, (size_t)Mrows * 8, stream);

    dim3 blk(256);
    // dtype prep
    cvt_bf16<<<dim3(Mrows * Dm / 2048), blk, 0, stream>>>(hs, hsbf);
    transpose_cvt3<<<dim3(Dm / 64, Dm / 64, 3), blk, 0, stream>>>(Wq, Wk, Wo, WqT, WkT, WoT);
    // Q,K projections fused via z (128x128-tile MFMA GEMM, 512 threads)
    gemm_bf16<true><<<dim3(Dm / 128, Mrows / 128, 2), dim3(512), 0, stream>>>(
        hsbf, WqT, WkT, bq, bk, qbf, kbf, Dm, Dm);
    // retrieval: split-K exact vq, reduce(+bf16 copy), screen, exact rescore
    gemm_vq_partial<<<dim3(DRr / 64, Mrows / 64, 4), blk, 0, stream>>>(hs, Wvq, vqp);
    reduce_vq<<<dim3(Mrows * DRr / 1024), blk, 0, stream>>>(vqp, bvq, vqb, vq_hi);
    cvt_bf16<<<dim3(NV * DRr / 2048), blk, 0, stream>>>(vkeys, vk_hi);
    sim_pass<0><<<dim3(Mrows / 64, 8), blk, 0, stream>>>(vq_hi, vk_hi, pm1, nullptr, nullptr);
    sim_pass<1><<<dim3(Mrows / 64, 8), blk, 0, stream>>>(vq_hi, vk_hi, pm1, cnt, pairs);
    sim_rescore<<<dim3(256), blk, 0, stream>>>(pairs, cnt, vqb, vkeys, best);
    // fused build+transpose of V, then mean
    build_vt<<<dim3(Ss / 64, Bb * Hh), blk, 0, stream>>>(hs, vembed, best, vtb);
    mean_vt<<<dim3(Bb * Hh), blk, 0, stream>>>(vtb, mvb);
    // attention (512 threads)
    attn_mfma4<<<dim3(Ss / 128, Hh, Bb), dim3(512), 0, stream>>>(
        qbf, kbf, vtb, amask, dmask, mvb, attno);
    // output projection (f32 out)
    gemm_bf16<false><<<dim3(Dm / 128, Mrows / 128, 1), dim3(512), 0, stream>>>(
        attno, WoT, WoT, bo, bo, out, out, Dm, Dm);
}

// Round 8
// 266.908 us; speedup vs baseline: 2.1218x; 1.0009x over previous
//
#include <hip/hip_runtime.h>
#include <hip/hip_bf16.h>
#include <math.h>

#define MIN_D (-3.402823466e+38f)

constexpr int Bb = 2, Ss = 2048, Dm = 1024, Hh = 16, HDd = 64, NV = 8192, DRr = 128;
constexpr int Mrows = Bb * Ss;   // 4096
constexpr float MARGIN = 0.01f;  // ~22 sigma of bf16 sim error (4.5e-4)
constexpr int CAP = 65536;       // candidate-pair buffer
constexpr float C2 = 0.18033688011112042f;   // 0.125 * log2(e)

typedef __attribute__((ext_vector_type(8))) short bf16x8;
typedef __attribute__((ext_vector_type(4))) float f32x4;

__device__ inline unsigned short f2bf(float x) {
    union { float f; unsigned u; } v; v.f = x;
    unsigned r = v.u + 0x7fff + ((v.u >> 16) & 1);   // RNE
    return (unsigned short)(r >> 16);
}
__device__ inline float bf2f(unsigned short u) {
    union { unsigned u; float f; } v; v.u = ((unsigned)u) << 16;
    return v.f;
}
__device__ inline unsigned pk_bf16(float a, float b) {   // native cvt_pk
    float2 t; t.x = a; t.y = b;
    __hip_bfloat162 h = __float22bfloat162_rn(t);
    return *(unsigned*)&h;
}

// ---------------------------------------------------------------------------
// f32 -> bf16 elementwise. 8 elems/thread; grid = n/2048.
// ---------------------------------------------------------------------------
__global__ __launch_bounds__(256)
void cvt_bf16(const float* __restrict__ x, unsigned short* __restrict__ y)
{
    size_t i = ((size_t)blockIdx.x * 256 + threadIdx.x) * 8;
    float4 a = *(const float4*)(x + i);
    float4 b = *(const float4*)(x + i + 4);
    uint4 p;
    p.x = pk_bf16(a.x, a.y);
    p.y = pk_bf16(a.z, a.w);
    p.z = pk_bf16(b.x, b.y);
    p.w = pk_bf16(b.z, b.w);
    *(uint4*)(y + i) = p;
}

// ---------------------------------------------------------------------------
// Fused transpose+convert of the three 1024x1024 weights (z selects).
// ---------------------------------------------------------------------------
__global__ __launch_bounds__(256)
void transpose_cvt3(const float* __restrict__ W0, const float* __restrict__ W1,
                    const float* __restrict__ W2, unsigned short* __restrict__ T0,
                    unsigned short* __restrict__ T1, unsigned short* __restrict__ T2)
{
    const float* W = blockIdx.z == 0 ? W0 : (blockIdx.z == 1 ? W1 : W2);
    unsigned short* WT = blockIdx.z == 0 ? T0 : (blockIdx.z == 1 ? T1 : T2);
    __shared__ unsigned short T[64][72];
    const int tid = threadIdx.x;
    const int n0 = blockIdx.x * 64, k0 = blockIdx.y * 64;
    const int rr = tid >> 4, cc = tid & 15;
#pragma unroll
    for (int q2 = 0; q2 < 4; ++q2) {
        int kk = rr * 4 + q2;
        float4 v = *(const float4*)(W + (size_t)(k0 + kk) * Dm + n0 + cc * 4);
        T[cc * 4 + 0][kk] = f2bf(v.x);
        T[cc * 4 + 1][kk] = f2bf(v.y);
        T[cc * 4 + 2][kk] = f2bf(v.z);
        T[cc * 4 + 3][kk] = f2bf(v.w);
    }
    __syncthreads();
#pragma unroll
    for (int q2 = 0; q2 < 4; ++q2) {
        int nn = rr * 4 + q2;
        uint2 u;
        u.x = (unsigned)T[nn][cc * 4 + 0] | ((unsigned)T[nn][cc * 4 + 1] << 16);
        u.y = (unsigned)T[nn][cc * 4 + 2] | ((unsigned)T[nn][cc * 4 + 3] << 16);
        *(uint2*)(WT + (size_t)(n0 + nn) * Dm + k0 + cc * 4) = u;
    }
}

// ---------------------------------------------------------------------------
// bf16 MFMA GEMM, 128x128 tile, 512 thr = 8 waves (2m x 4n), BK=32.
// Dual-target via blockIdx.z.
// ---------------------------------------------------------------------------
template<bool BF16OUT>
__global__ __launch_bounds__(512)
void gemm_bf16(const unsigned short* __restrict__ A,
               const unsigned short* BT0, const unsigned short* BT1,
               const float* bias0, const float* bias1,
               void* C0, void* C1, int N, int K)
{
    const unsigned short* BT = blockIdx.z ? BT1 : BT0;
    const float* bias = blockIdx.z ? bias1 : bias0;
    void* C = blockIdx.z ? C1 : C0;
    __shared__ __align__(16) unsigned short As[128 * 32];
    __shared__ __align__(16) unsigned short Bs[128 * 32];
    const int tid = threadIdx.x;
    const int l = tid & 63, w = tid >> 6;
    const int l15 = l & 15, l4 = l >> 4;
    const int wm = w >> 2, wn = w & 3;           // 2 x 4 wave grid
    const int row0 = blockIdx.y * 128, col0 = blockIdx.x * 128;

    f32x4 acc[4][2];
#pragma unroll
    for (int mi = 0; mi < 4; ++mi)
#pragma unroll
        for (int ni = 0; ni < 2; ++ni) acc[mi][ni] = (f32x4)(0.f);

    for (int k0 = 0; k0 < K; k0 += 32) {
        __syncthreads();
        {
            int r = tid >> 2, pc = tid & 3;
            uint4 vv = *(const uint4*)(A + (size_t)(row0 + r) * K + k0 + pc * 8);
            *(uint4*)&As[tid * 8] = vv;
        }
        {
            int r = tid >> 2, pc = tid & 3;
            uint4 vv = *(const uint4*)(BT + (size_t)(col0 + r) * K + k0 + pc * 8);
            *(uint4*)&Bs[tid * 8] = vv;
        }
        __syncthreads();

        bf16x8 af[4], bf[2];
#pragma unroll
        for (int mi = 0; mi < 4; ++mi)
            af[mi] = *(bf16x8*)&As[(wm * 64 + mi * 16 + l15) * 32 + l4 * 8];
#pragma unroll
        for (int ni = 0; ni < 2; ++ni)
            bf[ni] = *(bf16x8*)&Bs[(wn * 32 + ni * 16 + l15) * 32 + l4 * 8];
#pragma unroll
        for (int mi = 0; mi < 4; ++mi)
#pragma unroll
            for (int ni = 0; ni < 2; ++ni)
                acc[mi][ni] = __builtin_amdgcn_mfma_f32_16x16x32_bf16(af[mi], bf[ni], acc[mi][ni], 0, 0, 0);
    }

#pragma unroll
    for (int mi = 0; mi < 4; ++mi)
#pragma unroll
        for (int ni = 0; ni < 2; ++ni)
#pragma unroll
            for (int j = 0; j < 4; ++j) {
                int row = row0 + wm * 64 + mi * 16 + l4 * 4 + j;
                int col = col0 + wn * 32 + ni * 16 + l15;
                float vv = acc[mi][ni][j] + bias[col];
                if (BF16OUT)
                    ((unsigned short*)C)[(size_t)row * N + col] = f2bf(vv);
                else
                    ((float*)C)[(size_t)row * N + col] = vv;
            }
}

// ---------------------------------------------------------------------------
// Split-K f32 GEMM for vq: partial[z] = A[:, z*256:(z+1)*256] @ W-slice.
// ---------------------------------------------------------------------------
__global__ __launch_bounds__(256)
void gemm_vq_partial(const float* __restrict__ A, const float* __restrict__ W,
                     float* __restrict__ P)
{
    __shared__ float As[64][36];
    __shared__ float Ws[32][64];
    const int tid = threadIdx.x;
    const int row0 = blockIdx.y * 64, col0 = blockIdx.x * 64;
    const int kbase = blockIdx.z * 256;
    const int tr = tid >> 4, tc = tid & 15;
    float acc[4][4] = {};

    for (int k0 = kbase; k0 < kbase + 256; k0 += 32) {
        __syncthreads();
#pragma unroll
        for (int q2 = 0; q2 < 2; ++q2) {
            int oc = q2 * 256 + tid;
            int r = oc >> 3, c4 = (oc & 7) << 2;
            *(float4*)&As[r][c4] = *(const float4*)(A + (size_t)(row0 + r) * Dm + k0 + c4);
        }
#pragma unroll
        for (int q2 = 0; q2 < 2; ++q2) {
            int oc = q2 * 256 + tid;
            int r = oc >> 4, c4 = (oc & 15) << 2;
            *(float4*)&Ws[r][c4] = *(const float4*)(W + (size_t)(k0 + r) * DRr + col0 + c4);
        }
        __syncthreads();
#pragma unroll 8
        for (int kk = 0; kk < 32; ++kk) {
            float a[4];
#pragma unroll
            for (int i = 0; i < 4; ++i) a[i] = As[tr * 4 + i][kk];
            float4 bv = *(const float4*)&Ws[kk][tc * 4];
            float b[4] = {bv.x, bv.y, bv.z, bv.w};
#pragma unroll
            for (int i = 0; i < 4; ++i)
#pragma unroll
                for (int j = 0; j < 4; ++j)
                    acc[i][j] = fmaf(a[i], b[j], acc[i][j]);
        }
    }
    float* Pz = P + (size_t)blockIdx.z * Mrows * DRr;
#pragma unroll
    for (int i = 0; i < 4; ++i) {
        int r = row0 + tr * 4 + i;
        float4 ov = {acc[i][0], acc[i][1], acc[i][2], acc[i][3]};
        *(float4*)(Pz + (size_t)r * DRr + col0 + tc * 4) = ov;
    }
}

// ---------------------------------------------------------------------------
// Reduce split-K partials (fixed order) + bias -> vqb f32 and vq_hi bf16.
// ---------------------------------------------------------------------------
__global__ __launch_bounds__(256)
void reduce_vq(const float* __restrict__ P, const float* __restrict__ bias,
               float* __restrict__ vqb, unsigned short* __restrict__ vq_hi)
{
    const size_t i4 = ((size_t)blockIdx.x * 256 + threadIdx.x) * 4;
    const int col = (int)(i4 & 127);
    const size_t stride = (size_t)Mrows * DRr;
    float4 s = *(const float4*)(P + i4);
#pragma unroll
    for (int z = 1; z < 4; ++z) {
        float4 p = *(const float4*)(P + stride * z + i4);
        s.x += p.x; s.y += p.y; s.z += p.z; s.w += p.w;
    }
    float4 bv = *(const float4*)(bias + col);
    s.x += bv.x; s.y += bv.y; s.z += bv.z; s.w += bv.w;
    *(float4*)(vqb + i4) = s;
    uint2 u;
    u.x = pk_bf16(s.x, s.y);
    u.y = pk_bf16(s.z, s.w);
    *(uint2*)(vq_hi + i4) = u;
}

// ---------------------------------------------------------------------------
// Retrieval screen passes v2: 1024 blocks (4/CU), T14 async-STAGE split +
// double-buffered K tiles, one barrier/iter. Grid (Mrows/64, 16 chunks of 512).
// Block 256 thr = 4 waves; lane owns q = row0 + w*16 + l15 (swapped MFMA).
// Buf[0] doubles as the VQ staging area (prologue only).
// PASS 0: per-(row,chunk) bf16 max -> pm1[row][16].
// PASS 1: thr = max_c pm1 - MARGIN; push candidates >= thr.
// ---------------------------------------------------------------------------
template<int PASS>
__global__ __launch_bounds__(256)
void sim_pass(const unsigned short* __restrict__ vq_hi,
              const unsigned short* __restrict__ vk_hi,
              float* __restrict__ pm1,
              unsigned* __restrict__ cnt, unsigned* __restrict__ pairs)
{
    __shared__ __align__(16) unsigned short Buf[2][64 * 128];   // 32KB dbuf
    __shared__ float thrs[64];
    const int tid = threadIdx.x;
    const int l = tid & 63, w = tid >> 6;
    const int l15 = l & 15, l4 = l >> 4;
    const int row0 = blockIdx.x * 64;
    const int key0 = blockIdx.y * 512;
    const int qloc = w * 16 + l15;
    const int q = row0 + qloc;

    if (PASS == 1 && tid < 64) {
        const float* pp = pm1 + (size_t)(row0 + tid) * 16;
        float m = pp[0];
#pragma unroll
        for (int c = 1; c < 16; ++c) m = fmaxf(m, pp[c]);
        thrs[tid] = m - MARGIN;
    }
    // prologue: stage VQ into Buf[0]
#pragma unroll
    for (int q2 = 0; q2 < 4; ++q2) {
        int oc = q2 * 256 + tid;
        int r = oc >> 4, pc = oc & 15;
        int lc = pc ^ (r & 7);
        uint4 vv = *(const uint4*)(vq_hi + (size_t)(row0 + r) * 128 + lc * 8);
        *(uint4*)&Buf[0][oc * 8] = vv;
    }
    __syncthreads();
    bf16x8 qf[4];
#pragma unroll
    for (int kk = 0; kk < 4; ++kk)
        qf[kk] = *(bf16x8*)&Buf[0][qloc * 128 + (((kk * 4 + l4) ^ (qloc & 7)) * 8)];
    // stage K tile 0 into Buf[1] (ds ops; qf reads above are fenced by barrier)
    {
        const int r = tid >> 2, pc4 = tid & 3;
#pragma unroll
        for (int q2 = 0; q2 < 4; ++q2) {
            int rr = (q2 << 4) + r;   // careful: need rows 0..63, 4 chunks each
        }
    }
    // (restructured below: thread oc covers 4 chunk-positions of 64 rows)
#pragma unroll
    for (int q2 = 0; q2 < 4; ++q2) {
        int oc = q2 * 256 + tid;
        int r = oc >> 4, pc = oc & 15;
        int lc = pc ^ (r & 7);
        uint4 vv = *(const uint4*)(vk_hi + (size_t)(key0 + r) * 128 + lc * 8);
        *(uint4*)&Buf[1][oc * 8] = vv;
    }
    __syncthreads();   // K0 visible; qf reads complete -> Buf[0] reusable

    float th = (PASS == 1) ? thrs[qloc] : 0.f;
    float vmax = -INFINITY;

    for (int t = 0; t < 8; ++t) {
        const int cur = (t & 1) ^ 1;       // t even -> Buf[1], odd -> Buf[0]
        // T14: issue next tile's loads into registers BEFORE compute
        uint4 st[4];
        if (t + 1 < 8) {
#pragma unroll
            for (int q2 = 0; q2 < 4; ++q2) {
                int oc = q2 * 256 + tid;
                int r = oc >> 4, pc = oc & 15;
                int lc = pc ^ (r & 7);
                st[q2] = *(const uint4*)(vk_hi + (size_t)(key0 + (t + 1) * 64 + r) * 128 + lc * 8);
            }
        }
        // compute tile t from Buf[cur]
#pragma unroll
        for (int kb = 0; kb < 4; ++kb) {
            const int key16 = kb * 16 + l15;
            f32x4 s = (f32x4)(0.f);
#pragma unroll
            for (int kk = 0; kk < 4; ++kk) {
                bf16x8 kfr = *(bf16x8*)&Buf[cur][key16 * 128 + (((kk * 4 + l4) ^ (key16 & 7)) * 8)];
                s = __builtin_amdgcn_mfma_f32_16x16x32_bf16(kfr, qf[kk], s, 0, 0, 0);
            }
            if (PASS == 0) {
#pragma unroll
                for (int r = 0; r < 4; ++r) vmax = fmaxf(vmax, s[r]);
            } else {
#pragma unroll
                for (int r = 0; r < 4; ++r) {
                    if (s[r] >= th) {
                        int key = key0 + t * 64 + kb * 16 + l4 * 4 + r;
                        unsigned slot = atomicAdd(cnt, 1u);
                        if (slot < (unsigned)CAP)
                            pairs[slot] = ((unsigned)q << 13) | (unsigned)key;
                    }
                }
            }
        }
        // write staged registers into the other buffer (vmcnt wait lands here)
        if (t + 1 < 8) {
#pragma unroll
            for (int q2 = 0; q2 < 4; ++q2) {
                int oc = q2 * 256 + tid;
                *(uint4*)&Buf[cur ^ 1][oc * 8] = st[q2];
            }
        }
        __syncthreads();
    }
    if (PASS == 0) {
        vmax = fmaxf(vmax, __shfl_xor(vmax, 16));
        vmax = fmaxf(vmax, __shfl_xor(vmax, 32));
        if (l4 == 0) pm1[(size_t)q * 16 + blockIdx.y] = vmax;
    }
}

// ---------------------------------------------------------------------------
// Exact f32 rescore; first-index argmax via u64 atomicMax.
// ---------------------------------------------------------------------------
__global__ __launch_bounds__(256)
void sim_rescore(const unsigned* __restrict__ pairs, const unsigned* __restrict__ cnt,
                 const float* __restrict__ vq, const float* __restrict__ vkeys,
                 unsigned long long* __restrict__ best)
{
    const int l = threadIdx.x & 63;
    const unsigned wav = (blockIdx.x * 256 + threadIdx.x) >> 6;
    const unsigned nw = (gridDim.x * 256) >> 6;
    const unsigned n = min(*cnt, (unsigned)CAP);
    for (unsigned i = wav; i < n; i += nw) {
        unsigned p = pairs[i];
        unsigned row = p >> 13, key = p & 8191u;
        float2 a = *(const float2*)(vq + (size_t)row * 128 + l * 2);
        float2 b = *(const float2*)(vkeys + (size_t)key * 128 + l * 2);
        float d = a.x * b.x + a.y * b.y;
#pragma unroll
        for (int off = 32; off; off >>= 1) d += __shfl_xor(d, off);
        if (l == 0) {
            unsigned fb = __float_as_uint(d);
            fb = (fb & 0x80000000u) ? ~fb : (fb | 0x80000000u);
            unsigned long long enc = ((unsigned long long)fb << 32) | (unsigned)(~key);
            atomicMax(best + row, enc);
        }
    }
}

// ---------------------------------------------------------------------------
// Fused build + transpose: VT[(b*16+h)*64 + d][key] = bf16(hs * vembed[idx]).
// ---------------------------------------------------------------------------
__global__ __launch_bounds__(256)
void build_vt(const float* __restrict__ hs, const float* __restrict__ vembed,
              const unsigned long long* __restrict__ best,
              unsigned short* __restrict__ vt)
{
    __shared__ unsigned short T[64][73];
    __shared__ int ids[64];
    const int tid = threadIdx.x;
    const int kt = blockIdx.x;
    const int bh = blockIdx.y;
    const int b = bh >> 4, h = bh & 15;
    if (tid < 64) {
        int row = b * Ss + kt * 64 + tid;
        ids[tid] = (int)((~(unsigned)(best[row] & 0xFFFFFFFFull)) & 8191u);
    }
    __syncthreads();
    {
        int r = tid >> 2, c16 = (tid & 3) * 16;
        size_t hrow = (size_t)(b * Ss + kt * 64 + r) * Dm + h * HDd + c16;
        size_t erow = (size_t)ids[r] * Dm + h * HDd + c16;
#pragma unroll
        for (int q2 = 0; q2 < 4; ++q2) {
            float4 a = *(const float4*)(hs + hrow + q2 * 4);
            float4 e = *(const float4*)(vembed + erow + q2 * 4);
            T[r][c16 + q2 * 4 + 0] = f2bf(a.x * e.x);
            T[r][c16 + q2 * 4 + 1] = f2bf(a.y * e.y);
            T[r][c16 + q2 * 4 + 2] = f2bf(a.z * e.z);
            T[r][c16 + q2 * 4 + 3] = f2bf(a.w * e.w);
        }
    }
    __syncthreads();
    {
        int d = tid >> 2, kc = (tid & 3) * 16;
        unsigned short ob[16];
#pragma unroll
        for (int i = 0; i < 16; ++i) ob[i] = T[kc + i][d];
        unsigned short* op = vt + ((size_t)(b * Hh + h) * HDd + d) * Ss + kt * 64 + kc;
        *(uint4*)op = *(uint4*)&ob[0];
        *(uint4*)(op + 8) = *(uint4*)&ob[8];
    }
}

// ---------------------------------------------------------------------------
// meanv[b][h*64+d] from VT row sums (fully-masked-row substitution value).
// ---------------------------------------------------------------------------
__global__ __launch_bounds__(256)
void mean_vt(const unsigned short* __restrict__ vt, float* __restrict__ mv)
{
    const int bh = blockIdx.x;
    const int b = bh >> 4, h = bh & 15;
    const int d = threadIdx.x >> 2, part = threadIdx.x & 3;
    const unsigned short* row = vt + ((size_t)bh * HDd + d) * Ss + part * 512;
    float s = 0.f;
    for (int j = 0; j < 512; j += 8) {
        uint4 u = *(const uint4*)(row + j);
        const unsigned uu[4] = {u.x, u.y, u.z, u.w};
#pragma unroll
        for (int m = 0; m < 4; ++m) {
            s += bf2f((unsigned short)(uu[m] & 0xffff));
            s += bf2f((unsigned short)(uu[m] >> 16));
        }
    }
    s += __shfl_xor(s, 1);
    s += __shfl_xor(s, 2);
    if (part == 0) mv[b * Dm + h * HDd + d] = s * (1.f / 2048.f);
}

// ---------------------------------------------------------------------------
// bf16 MFMA flash attention v4 (unchanged): QBLK=128/8 waves, swapped QK^T,
// pre-transposed V, log2 softmax + defer-rescale, balanced qt pairing.
// ---------------------------------------------------------------------------
__global__ __launch_bounds__(512)
void attn_mfma4(const unsigned short* __restrict__ q, const unsigned short* __restrict__ k,
                const unsigned short* __restrict__ vt, const float* __restrict__ am,
                const float* __restrict__ dmask, const float* __restrict__ meanv,
                unsigned short* __restrict__ o)
{
    __shared__ __align__(16) unsigned char smem[40960]; // K 8K | VT 8K | P 16K | amdm 8K
    __shared__ float uniflag[128];
    unsigned char* Ksm = smem;
    unsigned char* Vsm = smem + 8192;
    unsigned char* Psm = smem + 16384;
    float* amdmf = (float*)(smem + 32768);

    const int tid = threadIdx.x;
    const int l = tid & 63, w = tid >> 6;
    const int l15 = l & 15, l4 = l >> 4;
    const int lin = blockIdx.x + (blockIdx.y << 4) + (blockIdx.z << 8);
    const int half = lin >> 8, rem = lin & 255;
    const int qtb = rem & 15;
    const int qt = half ? (15 - qtb) : qtb;
    const int h = rem >> 4;
    const int b = half;
    const int row0 = qt * 128;

    {
        int j = tid * 4;
        float4 a = *(const float4*)(am + b * Ss + j);
        float4 d = *(const float4*)(dmask + h * Ss + j);
        float4 m;
        m.x = (a.x * d.x == 0.f) ? MIN_D : 0.f;
        m.y = (a.y * d.y == 0.f) ? MIN_D : 0.f;
        m.z = (a.z * d.z == 0.f) ? MIN_D : 0.f;
        m.w = (a.w * d.w == 0.f) ? MIN_D : 0.f;
        *(float4*)&amdmf[j] = m;
    }

    const int qloc = w * 16 + l15;
    const int qrow = row0 + qloc;
    bf16x8 qf[2];
    {
        const unsigned short* qp = q + ((size_t)(b * Ss + qrow)) * Dm + h * HDd + l4 * 8;
        qf[0] = *(const bf16x8*)qp;
        qf[1] = *(const bf16x8*)(qp + 32);
    }

    f32x4 acc[4];
#pragma unroll
    for (int d2 = 0; d2 < 4; ++d2) acc[d2] = (f32x4)(0.f);
    float mrun = -INFINITY, lrun = 0.f;
    const int ktmax = 2 * qt + 1;

    for (int kt = 0; kt <= ktmax; ++kt) {
        __syncthreads();
        {
            int key = tid >> 3, pc = tid & 7, lc = pc ^ (key & 7);
            uint4 vv = *(const uint4*)(k + ((size_t)(b * Ss + kt * 64 + key)) * Dm
                                       + h * HDd + lc * 8);
            *(uint4*)&Ksm[tid * 16] = vv;
        }
        {
            int d = tid >> 3, pc = tid & 7, lc = pc ^ (d & 7);
            uint4 vv = *(const uint4*)(vt + ((size_t)(b * Hh + h) * HDd + d) * Ss
                                       + kt * 64 + lc * 8);
            *(uint4*)&Vsm[tid * 16] = vv;
        }
        __syncthreads();

        f32x4 sreg[4];
#pragma unroll
        for (int kb = 0; kb < 4; ++kb) {
            const int key16 = kb * 16 + l15;
            const int sw = key16 & 7;
            bf16x8 k0 = *(bf16x8*)&Ksm[key16 * 128 + ((l4 ^ sw) * 16)];
            bf16x8 k1 = *(bf16x8*)&Ksm[key16 * 128 + (((4 + l4) ^ sw) * 16)];
            f32x4 s = (f32x4)(0.f);
            s = __builtin_amdgcn_mfma_f32_16x16x32_bf16(k0, qf[0], s, 0, 0, 0);
            s = __builtin_amdgcn_mfma_f32_16x16x32_bf16(k1, qf[1], s, 0, 0, 0);
            sreg[kb] = s;
        }

        float sv[16];
#pragma unroll
        for (int kb = 0; kb < 4; ++kb)
#pragma unroll
            for (int r = 0; r < 4; ++r) {
                const int key = kt * 64 + kb * 16 + l4 * 4 + r;
                const float mval = (key > qrow) ? MIN_D : amdmf[key];
                sv[kb * 4 + r] = fmaf(sreg[kb][r], C2, mval);
            }

        float pm = fmaxf(fmaxf(sv[0], sv[1]), sv[2]);
        pm = fmaxf(fmaxf(pm, sv[3]), fmaxf(sv[4], sv[5]));
        pm = fmaxf(fmaxf(pm, sv[6]), fmaxf(sv[7], sv[8]));
        pm = fmaxf(fmaxf(pm, sv[9]), fmaxf(sv[10], sv[11]));
        pm = fmaxf(fmaxf(pm, sv[12]), fmaxf(sv[13], sv[14]));
        pm = fmaxf(pm, sv[15]);
        pm = fmaxf(pm, __shfl_xor(pm, 16));
        pm = fmaxf(pm, __shfl_xor(pm, 32));

        if (__any(pm > mrun + 8.f)) {
            const float mn = fmaxf(mrun, pm);
            const float sc = __builtin_amdgcn_exp2f(mrun - mn);
            lrun *= sc;
#pragma unroll
            for (int d2 = 0; d2 < 4; ++d2) acc[d2] *= sc;
            mrun = mn;
        }

        float p[16], rs = 0.f;
#pragma unroll
        for (int i = 0; i < 16; ++i) {
            p[i] = __builtin_amdgcn_exp2f(sv[i] - mrun);
            rs += p[i];
        }
        rs += __shfl_xor(rs, 16);
        rs += __shfl_xor(rs, 32);
        lrun += rs;

        const unsigned pswz = (l15 & 7) << 4;
#pragma unroll
        for (int kb = 0; kb < 4; ++kb) {
            uint2 u;
            u.x = pk_bf16(p[kb * 4 + 0], p[kb * 4 + 1]);
            u.y = pk_bf16(p[kb * 4 + 2], p[kb * 4 + 3]);
            *(uint2*)&Psm[qloc * 128 + ((kb * 32 + l4 * 8) ^ pswz)] = u;
        }

#pragma unroll
        for (int ks = 0; ks < 2; ++ks) {
            bf16x8 pa = *(bf16x8*)&Psm[qloc * 128 + ((ks * 64 + l4 * 16) ^ pswz)];
#pragma unroll
            for (int d2 = 0; d2 < 4; ++d2) {
                const int dd = d2 * 16 + l15;
                bf16x8 vb = *(bf16x8*)&Vsm[dd * 128 + ((ks * 64 + l4 * 16) ^ ((dd & 7) << 4))];
                acc[d2] = __builtin_amdgcn_mfma_f32_16x16x32_bf16(vb, pa, acc[d2], 0, 0, 0);
            }
        }
    }

    const float inv = 1.f / lrun;
    const bool uni = (mrun <= -1e37f);
    __syncthreads();
    unsigned short* stg = (unsigned short*)smem;
    uniflag[qloc] = uni ? 1.f : 0.f;
#pragma unroll
    for (int d2 = 0; d2 < 4; ++d2) {
        uint2 u;
        u.x = pk_bf16(acc[d2][0] * inv, acc[d2][1] * inv);
        u.y = pk_bf16(acc[d2][2] * inv, acc[d2][3] * inv);
        *(uint2*)&stg[qloc * 72 + d2 * 16 + l4 * 4] = u;
    }
    __syncthreads();
    {
        const int r = tid >> 2, c16 = (tid & 3) * 16;
        const bool u = uniflag[r] != 0.f;
        uint4 o0, o1;
        if (u) {
            unsigned short ob[16];
#pragma unroll
            for (int i = 0; i < 16; ++i)
                ob[i] = f2bf(meanv[b * Dm + h * HDd + c16 + i]);
            o0 = *(uint4*)&ob[0];
            o1 = *(uint4*)&ob[8];
        } else {
            o0 = *(uint4*)&stg[r * 72 + c16];
            o1 = *(uint4*)&stg[r * 72 + c16 + 8];
        }
        unsigned short* op = o + ((size_t)(b * Ss + row0 + r)) * Dm + h * HDd + c16;
        *(uint4*)op = o0;
        *(uint4*)(op + 8) = o1;
    }
}

// ---------------------------------------------------------------------------
extern "C" void kernel_launch(void* const* d_in, const int* in_sizes, int n_in,
                              void* d_out, int out_size, void* d_ws, size_t ws_size,
                              hipStream_t stream)
{
    const float* hs     = (const float*)d_in[0];
    const float* amask  = (const float*)d_in[1];
    const float* Wq     = (const float*)d_in[2];
    const float* bq     = (const float*)d_in[3];
    const float* Wk     = (const float*)d_in[4];
    const float* bk     = (const float*)d_in[5];
    const float* dmask  = (const float*)d_in[6];
    const float* Wvq    = (const float*)d_in[7];
    const float* bvq    = (const float*)d_in[8];
    const float* vkeys  = (const float*)d_in[9];
    const float* vembed = (const float*)d_in[10];
    const float* Wo     = (const float*)d_in[11];
    const float* bo     = (const float*)d_in[12];
    float* out = (float*)d_out;

    char* w = (char*)d_ws;
    size_t off = 0;
    auto take = [&](size_t n) { char* p = w + off; off = (off + n + 255) & ~(size_t)255; return p; };
    unsigned short* hsbf  = (unsigned short*)take((size_t)Mrows * Dm * 2);
    unsigned short* WqT   = (unsigned short*)take((size_t)Dm * Dm * 2);
    unsigned short* WkT   = (unsigned short*)take((size_t)Dm * Dm * 2);
    unsigned short* WoT   = (unsigned short*)take((size_t)Dm * Dm * 2);
    unsigned short* qbf   = (unsigned short*)take((size_t)Mrows * Dm * 2);
    unsigned short* kbf   = (unsigned short*)take((size_t)Mrows * Dm * 2);
    unsigned short* vtb   = (unsigned short*)take((size_t)Mrows * Dm * 2);   // VT
    unsigned short* attno = (unsigned short*)take((size_t)Mrows * Dm * 2);
    float* vqp   = (float*)take((size_t)4 * Mrows * DRr * 4);               // split-K partials
    float* vqb   = (float*)take((size_t)Mrows * DRr * 4);
    unsigned short* vq_hi = (unsigned short*)take((size_t)Mrows * DRr * 2);
    unsigned short* vk_hi = (unsigned short*)take((size_t)NV * DRr * 2);
    float* pm1   = (float*)take((size_t)Mrows * 16 * 4);
    unsigned* cnt = (unsigned*)take(256);
    unsigned* pairs = (unsigned*)take((size_t)CAP * 4);
    unsigned long long* best = (unsigned long long*)take((size_t)Mrows * 8);
    float* mvb   = (float*)take((size_t)Bb * Dm * 4);

    hipMemsetAsync(cnt, 0, 4, stream);
    hipMemsetAsync(best, 0, (size_t)Mrows * 8, stream);

    dim3 blk(256);
    // dtype prep
    cvt_bf16<<<dim3(Mrows * Dm / 2048), blk, 0, stream>>>(hs, hsbf);
    transpose_cvt3<<<dim3(Dm / 64, Dm / 64, 3), blk, 0, stream>>>(Wq, Wk, Wo, WqT, WkT, WoT);
    // Q,K projections fused via z
    gemm_bf16<true><<<dim3(Dm / 128, Mrows / 128, 2), dim3(512), 0, stream>>>(
        hsbf, WqT, WkT, bq, bk, qbf, kbf, Dm, Dm);
    // retrieval: split-K exact vq, reduce(+bf16 copy), screen, exact rescore
    gemm_vq_partial<<<dim3(DRr / 64, Mrows / 64, 4), blk, 0, stream>>>(hs, Wvq, vqp);
    reduce_vq<<<dim3(Mrows * DRr / 1024), blk, 0, stream>>>(vqp, bvq, vqb, vq_hi);
    cvt_bf16<<<dim3(NV * DRr / 2048), blk, 0, stream>>>(vkeys, vk_hi);
    sim_pass<0><<<dim3(Mrows / 64, 16), blk, 0, stream>>>(vq_hi, vk_hi, pm1, nullptr, nullptr);
    sim_pass<1><<<dim3(Mrows / 64, 16), blk, 0, stream>>>(vq_hi, vk_hi, pm1, cnt, pairs);
    sim_rescore<<<dim3(256), blk, 0, stream>>>(pairs, cnt, vqb, vkeys, best);
    // fused build+transpose of V, then mean
    build_vt<<<dim3(Ss / 64, Bb * Hh), blk, 0, stream>>>(hs, vembed, best, vtb);
    mean_vt<<<dim3(Bb * Hh), blk, 0, stream>>>(vtb, mvb);
    // attention (512 threads)
    attn_mfma4<<<dim3(Ss / 128, Hh, Bb), dim3(512), 0, stream>>>(
        qbf, kbf, vtb, amask, dmask, mvb, attno);
    // output projection (f32 out)
    gemm_bf16<false><<<dim3(Dm / 128, Mrows / 128, 1), dim3(512), 0, stream>>>(
        attno, WoT, WoT, bo, bo, out, out, Dm, Dm);
}